// Round 17
// baseline (144.274 us; speedup 1.0000x reference)
//
#include <hip/hip_runtime.h>
#include <hip/hip_bf16.h>

#define IN_DIM 512
#define HEADS 8
#define HID 8
#define OUT_DIM 7
#define NEG_SLOPE 0.2f

typedef __attribute__((ext_vector_type(8))) short short8b;   // 8 bf16 (4 VGPR)
typedef __attribute__((ext_vector_type(4))) float f32x4;

#define BSHIFT 7
#define BMASK 127
#define K3_EPT 16

__device__ __forceinline__ unsigned short f2bf_rne(float f) {
    unsigned u = __float_as_uint(f);
    unsigned r = (u + 0x7FFFu + ((u >> 16) & 1u)) >> 16;
    return (unsigned short)r;
}
__device__ __forceinline__ float bf2f(unsigned short s) {
    return __uint_as_float((unsigned)s << 16);
}

// ---------------- prep: W1 fragment-pack (blocks 0..127) || bucket hist (128..639)
__global__ __launch_bounds__(256) void prep_kernel(
    const float* __restrict__ W1, unsigned short* __restrict__ bhi,
    unsigned short* __restrict__ blo,
    const int* __restrict__ dst, int* __restrict__ bucketCounts, int E, int nbuck)
{
    __shared__ int cnt[512];
    int t = threadIdx.x;
    if (blockIdx.x < 128) {
        int i = blockIdx.x * 256 + t;       // 0..32767
        int j = i & 7;
        int lane = (i >> 3) & 63;
        int T = (i >> 9) & 3;
        int chunk = i >> 11;
        int col = 16 * T + (lane & 15);
        int k = chunk * 32 + 8 * (lane >> 4) + j;
        float w = W1[k * 64 + col];
        unsigned u = __float_as_uint(w);
        unsigned hu = u & 0xFFFF0000u;
        float rem = w - __uint_as_float(hu);
        bhi[i] = (unsigned short)(hu >> 16);
        blo[i] = (unsigned short)(__float_as_uint(rem) >> 16);
    } else {
        int b = blockIdx.x - 128;           // 0..511
        cnt[t] = 0; cnt[t + 256] = 0;
        __syncthreads();
        int i = b * 256 + t;
        int stride = 512 * 256;
        for (; i < E; i += stride) atomicAdd(&cnt[dst[i] >> BSHIFT], 1);
        __syncthreads();
        if (t < nbuck && cnt[t]) atomicAdd(&bucketCounts[t], cnt[t]);
        int t2 = t + 256;
        if (t2 < nbuck && cnt[t2]) atomicAdd(&bucketCounts[t2], cnt[t2]);
    }
}

__global__ __launch_bounds__(512) void bucket_scan_kernel(
    const int* __restrict__ bucketCounts, int* __restrict__ bucketBase,
    int* __restrict__ bucketCursor, int nbuck)
{
    __shared__ int wsum[8];
    int t = threadIdx.x, lane = t & 63, w = t >> 6;
    int c = (t < nbuck) ? bucketCounts[t] : 0;
    int inc = c;
    #pragma unroll
    for (int d = 1; d < 64; d <<= 1) {
        int u = __shfl_up(inc, d);
        if (lane >= d) inc += u;
    }
    if (lane == 63) wsum[w] = inc;
    __syncthreads();
    if (t == 0) { int run = 0; for (int k = 0; k < 8; ++k) { int tmp = wsum[k]; wsum[k] = run; run += tmp; } }
    __syncthreads();
    int excl = inc - c + wsum[w];
    if (t < nbuck) { bucketBase[t] = excl; bucketCursor[t] = excl; }
    if (t == nbuck) bucketBase[t] = excl;
}

// ---------------- fused: coarse scatter (blocks 0..nCoarse-1) || GEMM1 (rest)
// LDS halved to 17.4 KB via 2-phase k-staging -> ~9 blocks/CU resident.
__global__ __launch_bounds__(256) void gemm1_coarse_kernel(
    const float* __restrict__ x,
    const unsigned short* __restrict__ bhi, const unsigned short* __restrict__ blo,
    const float* __restrict__ as1, const float* __restrict__ ad1,
    unsigned short* __restrict__ h1, float* __restrict__ asrc1, float* __restrict__ adst1,
    int n,
    const int* __restrict__ src, const int* __restrict__ dstv,
    int* __restrict__ bucketCursor, unsigned int* __restrict__ tmp, int E, int nCoarse)
{
    __shared__ float lds[4][16][68];   // 17.4 KB: per-wave k-half stage / partials; coarse cnt+gbase
    int t = threadIdx.x;

    if ((int)blockIdx.x < nCoarse) {
        int* cnt   = (int*)&lds[0][0][0];
        int* gbase = cnt + 512;
        cnt[t] = 0; cnt[t + 256] = 0;
        __syncthreads();
        int base = blockIdx.x * (256 * K3_EPT);
        unsigned int pk[K3_EPT];
        unsigned int meta[K3_EPT];
        #pragma unroll
        for (int j = 0; j < K3_EPT; ++j) {
            int i = base + t + j * 256;
            if (i < E) {
                int d = dstv[i], s = src[i];
                int b = d >> BSHIFT;
                pk[j] = ((unsigned)s << 16) | (unsigned)(d & BMASK);
                int r = atomicAdd(&cnt[b], 1);
                meta[j] = ((unsigned)r << 9) | (unsigned)b;
            } else {
                meta[j] = 0xFFFFFFFFu; pk[j] = 0;
            }
        }
        __syncthreads();
        if (cnt[t] > 0) gbase[t] = atomicAdd(&bucketCursor[t], cnt[t]);
        int t2 = t + 256;
        if (cnt[t2] > 0) gbase[t2] = atomicAdd(&bucketCursor[t2], cnt[t2]);
        __syncthreads();
        #pragma unroll
        for (int j = 0; j < K3_EPT; ++j) {
            if (meta[j] != 0xFFFFFFFFu) {
                int b = meta[j] & 511;
                int r = meta[j] >> 9;
                tmp[gbase[b] + r] = pk[j];
            }
        }
        return;
    }

    // ---- GEMM1 part: wave owns k in [wave*128, wave*128+128), staged 64 at a time ----
    int wave = t >> 6, l = t & 63;
    int il = l & 15, g = l >> 4;
    int r0 = (blockIdx.x - nCoarse) * 16;
    int kw = wave * 128;

    f32x4 acc[4] = {{0.f,0.f,0.f,0.f},{0.f,0.f,0.f,0.f},{0.f,0.f,0.f,0.f},{0.f,0.f,0.f,0.f}};

    #pragma unroll
    for (int ph = 0; ph < 2; ++ph) {
        // stage 16 rows x 64 k: 4 float4 per lane, coalesced (256B/row halves)
        #pragma unroll
        for (int j = 0; j < 4; ++j) {
            int idx = j * 64 + l;          // 0..255
            int row = idx >> 4;            // 16 rows
            int kq = idx & 15;             // float4 slot in 64-float slice
            int gr = r0 + row; if (gr >= n) gr = n - 1;
            float4 v = *(const float4*)(x + (size_t)gr * IN_DIM + kw + ph * 64 + kq * 4);
            *(float4*)(&lds[wave][row][kq * 4]) = v;
        }
        // wave-local lgkm waits inserted by compiler; no barrier (per-wave buffer)
        #pragma unroll
        for (int itp = 0; itp < 2; ++itp) {
            int it = ph * 2 + itp;
            float av[8];
            *(float4*)(&av[0]) = *(const float4*)(&lds[wave][il][32 * itp + 8 * g]);
            *(float4*)(&av[4]) = *(const float4*)(&lds[wave][il][32 * itp + 8 * g + 4]);
            short8b Ahi, Alo;
            #pragma unroll
            for (int j = 0; j < 8; ++j) {
                unsigned u = __float_as_uint(av[j]);
                unsigned hu = u & 0xFFFF0000u;
                float rem = av[j] - __uint_as_float(hu);
                Ahi[j] = (short)(hu >> 16);
                Alo[j] = (short)(__float_as_uint(rem) >> 16);
            }
            int chunk = wave * 4 + it;
            const short8b* bh = (const short8b*)bhi + (size_t)(chunk * 4) * 64 + l;
            const short8b* bl = (const short8b*)blo + (size_t)(chunk * 4) * 64 + l;
            short8b Bh[4], Bl[4];
            #pragma unroll
            for (int T = 0; T < 4; ++T) { Bh[T] = bh[T * 64]; Bl[T] = bl[T * 64]; }
            #pragma unroll
            for (int T = 0; T < 4; ++T) {
                acc[T] = __builtin_amdgcn_mfma_f32_16x16x32_bf16(Alo, Bh[T], acc[T], 0, 0, 0);
                acc[T] = __builtin_amdgcn_mfma_f32_16x16x32_bf16(Ahi, Bl[T], acc[T], 0, 0, 0);
                acc[T] = __builtin_amdgcn_mfma_f32_16x16x32_bf16(Ahi, Bh[T], acc[T], 0, 0, 0);
            }
        }
    }

    // partials -> LDS (cols 0..63 fit stride 68), cross-wave reduce
    #pragma unroll
    for (int T = 0; T < 4; ++T)
        #pragma unroll
        for (int r = 0; r < 4; ++r)
            lds[wave][4 * g + r][16 * T + il] = acc[T][r];
    __syncthreads();

    int row = t >> 4, c0 = (t & 15) * 4;
    int grow = r0 + row;
    float v0 = lds[0][row][c0]     + lds[1][row][c0]     + lds[2][row][c0]     + lds[3][row][c0];
    float v1 = lds[0][row][c0 + 1] + lds[1][row][c0 + 1] + lds[2][row][c0 + 1] + lds[3][row][c0 + 1];
    float v2 = lds[0][row][c0 + 2] + lds[1][row][c0 + 2] + lds[2][row][c0 + 2] + lds[3][row][c0 + 2];
    float v3 = lds[0][row][c0 + 3] + lds[1][row][c0 + 3] + lds[2][row][c0 + 3] + lds[3][row][c0 + 3];
    if (grow < n) {
        ushort4 hb;
        hb.x = f2bf_rne(v0); hb.y = f2bf_rne(v1);
        hb.z = f2bf_rne(v2); hb.w = f2bf_rne(v3);
        *(ushort4*)(h1 + (size_t)grow * 64 + c0) = hb;
        float4 asv = *(const float4*)(as1 + c0);
        float4 adv = *(const float4*)(ad1 + c0);
        float pa = v0 * asv.x + v1 * asv.y + v2 * asv.z + v3 * asv.w;
        float pd = v0 * adv.x + v1 * adv.y + v2 * adv.z + v3 * adv.w;
        pa += __shfl_xor(pa, 1);
        pd += __shfl_xor(pd, 1);
        if ((t & 1) == 0) {
            int head = (t & 15) >> 1;
            asrc1[grow * 8 + head] = pa;
            adst1[grow * 8 + head] = pd;
        }
    }
}

__global__ __launch_bounds__(256) void fine_scatter_kernel(
    const unsigned int* __restrict__ tmp, const int* __restrict__ bucketBase,
    int* __restrict__ csr, int* __restrict__ offsets, int* __restrict__ counts, int n)
{
    __shared__ int cnt[128];
    __shared__ int cur[128];
    __shared__ int wsum[2];
    int b = blockIdx.x;
    int t = threadIdx.x, lane = t & 63, w = t >> 6;
    int beg = bucketBase[b], end = bucketBase[b + 1];
    if (t < 128) cnt[t] = 0;
    __syncthreads();
    for (int i = beg + t; i < end; i += 256)
        atomicAdd(&cnt[tmp[i] & BMASK], 1);
    __syncthreads();
    if (t < 128) {
        int c = cnt[t];
        int inc = c;
        #pragma unroll
        for (int d = 1; d < 64; d <<= 1) {
            int u = __shfl_up(inc, d);
            if (lane >= d) inc += u;
        }
        if (lane == 63) wsum[w] = inc;
        __syncthreads();
        if (t == 0) { int r0_ = wsum[0]; wsum[0] = 0; wsum[1] = r0_; }
        __syncthreads();
        int excl = inc - c + wsum[w];
        int node = b * 128 + t;
        if (node < n) { offsets[node] = beg + excl; counts[node] = c; }
        cur[t] = excl;
    } else {
        __syncthreads(); __syncthreads();
    }
    __syncthreads();
    for (int i = beg + t; i < end; i += 256) {
        unsigned int p = tmp[i];
        int r = atomicAdd(&cur[p & BMASK], 1);
        csr[beg + r] = (int)(p >> 16);
    }
}

// ---------------- Layer-1 edge kernel: single-pass, bf16 h1 gathers --------
__global__ __launch_bounds__(256) void l1_edge_kernel(
    const int* __restrict__ offsets, const int* __restrict__ counts,
    const int* __restrict__ csr,
    const float* __restrict__ asrc1, const float* __restrict__ adst1,
    const unsigned short* __restrict__ h1, const float* __restrict__ b1,
    const float* __restrict__ W2, const float* __restrict__ as2,
    const float* __restrict__ ad2,
    float* __restrict__ h2, float* __restrict__ asrc2, float* __restrict__ adst2,
    int n)
{
    __shared__ float w2t[8][64];
    __shared__ float s_as2[8], s_ad2[8], s_b1[64];
    __shared__ int csr_s[4][64];
    int t = threadIdx.x;
    if (t < 64) {
        #pragma unroll
        for (int j = 0; j < OUT_DIM; ++j) w2t[j][t] = W2[t * OUT_DIM + j];
        s_b1[t] = b1[t];
        if (t < OUT_DIM) { s_as2[t] = as2[t]; s_ad2[t] = ad2[t]; }
    }
    __syncthreads();

    int lane = t & 63;
    int nl = t >> 6;
    int node = blockIdx.x * 4 + nl;
    if (node >= n) return;
    int beg = offsets[node];
    int deg = counts[node];
    int q = lane >> 4;
    int il = lane & 15;
    int c0 = il * 4;
    int head = il >> 1;
    float adv = adst1[node * 8 + head];

    if (lane < deg) csr_s[nl][lane] = csr[beg + lane];
    int deg_r = deg < 64 ? deg : 64;
    const int* cs = &csr_s[nl][0];

    float4 acc = make_float4(0.f, 0.f, 0.f, 0.f);
    float ssum = 0.f;
    if (q == 0) {   // self loop
        float e = asrc1[node * 8 + head] + adv;
        e = e > 0.f ? e : NEG_SLOPE * e;
        float p = __expf(e);
        ushort4 hu = *(const ushort4*)(h1 + (size_t)node * 64 + c0);
        acc.x = p * bf2f(hu.x); acc.y = p * bf2f(hu.y);
        acc.z = p * bf2f(hu.z); acc.w = p * bf2f(hu.w);
        ssum = p;
    }
    int j = q;
    for (; j + 12 < deg_r; j += 16) {
        int s0 = cs[j];
        int s1 = cs[j + 4];
        int s2 = cs[j + 8];
        int s3 = cs[j + 12];
        float a0 = asrc1[s0 * 8 + head], a1 = asrc1[s1 * 8 + head];
        float a2 = asrc1[s2 * 8 + head], a3 = asrc1[s3 * 8 + head];
        ushort4 g0 = *(const ushort4*)(h1 + (size_t)s0 * 64 + c0);
        ushort4 g1 = *(const ushort4*)(h1 + (size_t)s1 * 64 + c0);
        ushort4 g2 = *(const ushort4*)(h1 + (size_t)s2 * 64 + c0);
        ushort4 g3 = *(const ushort4*)(h1 + (size_t)s3 * 64 + c0);
        float e0 = a0 + adv; e0 = e0 > 0.f ? e0 : NEG_SLOPE * e0;
        float e1 = a1 + adv; e1 = e1 > 0.f ? e1 : NEG_SLOPE * e1;
        float e2 = a2 + adv; e2 = e2 > 0.f ? e2 : NEG_SLOPE * e2;
        float e3 = a3 + adv; e3 = e3 > 0.f ? e3 : NEG_SLOPE * e3;
        float p0 = __expf(e0), p1 = __expf(e1);
        float p2 = __expf(e2), p3 = __expf(e3);
        acc.x = fmaf(p0, bf2f(g0.x), acc.x); acc.y = fmaf(p0, bf2f(g0.y), acc.y);
        acc.z = fmaf(p0, bf2f(g0.z), acc.z); acc.w = fmaf(p0, bf2f(g0.w), acc.w);
        acc.x = fmaf(p1, bf2f(g1.x), acc.x); acc.y = fmaf(p1, bf2f(g1.y), acc.y);
        acc.z = fmaf(p1, bf2f(g1.z), acc.z); acc.w = fmaf(p1, bf2f(g1.w), acc.w);
        acc.x = fmaf(p2, bf2f(g2.x), acc.x); acc.y = fmaf(p2, bf2f(g2.y), acc.y);
        acc.z = fmaf(p2, bf2f(g2.z), acc.z); acc.w = fmaf(p2, bf2f(g2.w), acc.w);
        acc.x = fmaf(p3, bf2f(g3.x), acc.x); acc.y = fmaf(p3, bf2f(g3.y), acc.y);
        acc.z = fmaf(p3, bf2f(g3.z), acc.z); acc.w = fmaf(p3, bf2f(g3.w), acc.w);
        ssum += (p0 + p1) + (p2 + p3);
    }
    for (; j < deg_r; j += 4) {
        int sn = cs[j];
        float a = asrc1[sn * 8 + head];
        ushort4 g = *(const ushort4*)(h1 + (size_t)sn * 64 + c0);
        float e = a + adv; e = e > 0.f ? e : NEG_SLOPE * e;
        float p = __expf(e);
        acc.x = fmaf(p, bf2f(g.x), acc.x); acc.y = fmaf(p, bf2f(g.y), acc.y);
        acc.z = fmaf(p, bf2f(g.z), acc.z); acc.w = fmaf(p, bf2f(g.w), acc.w);
        ssum += p;
    }
    for (; j < deg; j += 4) {
        int sn = csr[beg + j];
        float a = asrc1[sn * 8 + head];
        ushort4 g = *(const ushort4*)(h1 + (size_t)sn * 64 + c0);
        float e = a + adv; e = e > 0.f ? e : NEG_SLOPE * e;
        float p = __expf(e);
        acc.x = fmaf(p, bf2f(g.x), acc.x); acc.y = fmaf(p, bf2f(g.y), acc.y);
        acc.z = fmaf(p, bf2f(g.z), acc.z); acc.w = fmaf(p, bf2f(g.w), acc.w);
        ssum += p;
    }
    acc.x += __shfl_xor(acc.x, 16); acc.x += __shfl_xor(acc.x, 32);
    acc.y += __shfl_xor(acc.y, 16); acc.y += __shfl_xor(acc.y, 32);
    acc.z += __shfl_xor(acc.z, 16); acc.z += __shfl_xor(acc.z, 32);
    acc.w += __shfl_xor(acc.w, 16); acc.w += __shfl_xor(acc.w, 32);
    ssum  += __shfl_xor(ssum, 16);  ssum  += __shfl_xor(ssum, 32);
    float inv = 1.f / fmaxf(ssum, 1e-16f);

    float4 bv = *(const float4*)(&s_b1[c0]);
    float v0 = acc.x * inv + bv.x;
    float v1 = acc.y * inv + bv.y;
    float v2 = acc.z * inv + bv.z;
    float v3 = acc.w * inv + bv.w;
    v0 = v0 > 0.f ? v0 : __expf(v0) - 1.f;
    v1 = v1 > 0.f ? v1 : __expf(v1) - 1.f;
    v2 = v2 > 0.f ? v2 : __expf(v2) - 1.f;
    v3 = v3 > 0.f ? v3 : __expf(v3) - 1.f;

    float hj[OUT_DIM];
    #pragma unroll
    for (int jj = 0; jj < OUT_DIM; ++jj) {
        float4 wv = *(const float4*)(&w2t[jj][c0]);
        float p = v0 * wv.x + v1 * wv.y + v2 * wv.z + v3 * wv.w;
        p += __shfl_xor(p, 1);
        p += __shfl_xor(p, 2);
        p += __shfl_xor(p, 4);
        p += __shfl_xor(p, 8);
        hj[jj] = p;
    }
    float a_s = 0.f, a_d = 0.f;
    #pragma unroll
    for (int jj = 0; jj < OUT_DIM; ++jj) { a_s += hj[jj] * s_as2[jj]; a_d += hj[jj] * s_ad2[jj]; }
    if (lane < 8) h2[node * 8 + lane] = (lane < OUT_DIM) ? hj[lane] : 0.f;
    if (lane == 0) { asrc2[node] = a_s; adst2[node] = a_d; }
}

// ---------------- Layer-2 edge kernel: single-pass -> final logits --------
__global__ __launch_bounds__(256) void l2_edge_kernel(
    const int* __restrict__ offsets, const int* __restrict__ counts,
    const int* __restrict__ csr,
    const float* __restrict__ asrc2, const float* __restrict__ adst2,
    const float* __restrict__ h2, const float* __restrict__ b2,
    float* __restrict__ out, int n)
{
    int t = threadIdx.x, lane = t & 63;
    int node = blockIdx.x * 4 + (t >> 6);
    if (node >= n) return;
    int beg = offsets[node];
    int deg = counts[node];
    float adv = adst2[node];

    int c = lane & 7, slot = lane >> 3;
    float acc = 0.f, ssum = 0.f;
    if (slot == 0) {
        float e = asrc2[node] + adv;
        e = e > 0.f ? e : NEG_SLOPE * e;
        float p = __expf(e);
        acc = p * h2[node * 8 + c];
        ssum = p;
    }
    int j = slot;
    for (; j + 8 < deg; j += 16) {
        int s0 = csr[beg + j], s1 = csr[beg + j + 8];
        float a0 = asrc2[s0], a1 = asrc2[s1];
        float g0 = h2[s0 * 8 + c], g1 = h2[s1 * 8 + c];
        float e0 = a0 + adv; e0 = e0 > 0.f ? e0 : NEG_SLOPE * e0;
        float e1 = a1 + adv; e1 = e1 > 0.f ? e1 : NEG_SLOPE * e1;
        float p0 = __expf(e0), p1 = __expf(e1);
        acc = fmaf(p0, g0, acc); acc = fmaf(p1, g1, acc);
        ssum += p0 + p1;
    }
    for (; j < deg; j += 8) {
        int sn = csr[beg + j];
        float e = asrc2[sn] + adv;
        e = e > 0.f ? e : NEG_SLOPE * e;
        float p = __expf(e);
        acc = fmaf(p, h2[sn * 8 + c], acc);
        ssum += p;
    }
    acc  += __shfl_xor(acc, 8);  acc  += __shfl_xor(acc, 16);  acc  += __shfl_xor(acc, 32);
    ssum += __shfl_xor(ssum, 8); ssum += __shfl_xor(ssum, 16); ssum += __shfl_xor(ssum, 32);
    float inv = 1.f / fmaxf(ssum, 1e-16f);
    if (lane < OUT_DIM) out[(size_t)node * OUT_DIM + lane] = acc * inv + b2[lane];
}

// ---------------- launch ----------------
static inline size_t rup256(size_t x) { return (x + 255) & ~(size_t)255; }

extern "C" void kernel_launch(void* const* d_in, const int* in_sizes, int n_in,
                              void* d_out, int out_size, void* d_ws, size_t ws_size,
                              hipStream_t stream)
{
    int n = in_sizes[0] / IN_DIM;       // 50000
    int E = in_sizes[1] / 2;            // 1600000
    int nbuck = (n + BMASK) >> BSHIFT;  // 391
    int nCoarse = (E + 256 * K3_EPT - 1) / (256 * K3_EPT);   // 391

    const float* x   = (const float*)d_in[0];
    const int*   ei  = (const int*)d_in[1];
    const int*   srcv = ei;
    const int*   dstv = ei + E;
    const float* W1  = (const float*)d_in[2];
    const float* as1 = (const float*)d_in[3];
    const float* ad1 = (const float*)d_in[4];
    const float* b1  = (const float*)d_in[5];
    const float* W2  = (const float*)d_in[6];
    const float* as2 = (const float*)d_in[7];
    const float* ad2 = (const float*)d_in[8];
    const float* b2  = (const float*)d_in[9];
    float* out = (float*)d_out;

    char* p = (char*)d_ws;
    auto alloc = [&](size_t bytes) { char* q = p; p += rup256(bytes); return (void*)q; };
    unsigned short* h1 = (unsigned short*)alloc((size_t)n * 64 * 2);
    float* asrc1   = (float*)alloc((size_t)n * 8 * 4);
    float* adst1   = (float*)alloc((size_t)n * 8 * 4);
    float* h2      = (float*)alloc((size_t)n * 8 * 4);
    float* asrc2   = (float*)alloc((size_t)n * 4);
    float* adst2   = (float*)alloc((size_t)n * 4);
    int*   counts  = (int*)alloc((size_t)n * 4);
    int*   offsets = (int*)alloc(((size_t)n + 1) * 4);
    int*   csr     = (int*)alloc((size_t)E * 4);
    unsigned int* tmp = (unsigned int*)alloc((size_t)E * 4);
    int*   bucketCounts = (int*)alloc(512 * 4);
    int*   bucketBase   = (int*)alloc(513 * 4);
    int*   bucketCursor = (int*)alloc(512 * 4);
    unsigned short* bhi = (unsigned short*)alloc((size_t)IN_DIM * 64 * 2);
    unsigned short* blo = (unsigned short*)alloc((size_t)IN_DIM * 64 * 2);

    hipMemsetAsync(bucketCounts, 0, 512 * 4, stream);
    prep_kernel<<<128 + 512, 256, 0, stream>>>(W1, bhi, blo, dstv, bucketCounts, E, nbuck);
    bucket_scan_kernel<<<1, 512, 0, stream>>>(bucketCounts, bucketBase, bucketCursor, nbuck);
    gemm1_coarse_kernel<<<nCoarse + (n + 15) / 16, 256, 0, stream>>>(
        x, bhi, blo, as1, ad1, h1, asrc1, adst1, n,
        srcv, dstv, bucketCursor, tmp, E, nCoarse);
    fine_scatter_kernel<<<nbuck, 256, 0, stream>>>(
        tmp, bucketBase, csr, offsets, counts, n);
    l1_edge_kernel<<<(n + 3) / 4, 256, 0, stream>>>(
        offsets, counts, csr, asrc1, adst1, h1, b1, W2, as2, ad2, h2, asrc2, adst2, n);
    l2_edge_kernel<<<(n + 3) / 4, 256, 0, stream>>>(
        offsets, counts, csr, asrc2, adst2, h2, b2, out, n);
}

// Round 19
// 143.752 us; speedup vs baseline: 1.0036x; 1.0036x over previous
//
#include <hip/hip_runtime.h>
#include <hip/hip_bf16.h>

#define IN_DIM 512
#define HEADS 8
#define HID 8
#define OUT_DIM 7
#define NEG_SLOPE 0.2f

typedef __attribute__((ext_vector_type(8))) short short8b;   // 8 bf16 (4 VGPR)
typedef __attribute__((ext_vector_type(4))) float f32x4;

#define BSHIFT 7
#define BMASK 127
#define K3_EPT 16

__device__ __forceinline__ unsigned short f2bf_rne(float f) {
    unsigned u = __float_as_uint(f);
    unsigned r = (u + 0x7FFFu + ((u >> 16) & 1u)) >> 16;
    return (unsigned short)r;
}
__device__ __forceinline__ float bf2f(unsigned short s) {
    return __uint_as_float((unsigned)s << 16);
}

// ---------------- prep: W1 fragment-pack (blocks 0..127) || bucket hist (128..639)
__global__ __launch_bounds__(256) void prep_kernel(
    const float* __restrict__ W1, unsigned short* __restrict__ bhi,
    unsigned short* __restrict__ blo,
    const int* __restrict__ dst, int* __restrict__ bucketCounts, int E, int nbuck)
{
    __shared__ int cnt[512];
    int t = threadIdx.x;
    if (blockIdx.x < 128) {
        int i = blockIdx.x * 256 + t;       // 0..32767
        int j = i & 7;
        int lane = (i >> 3) & 63;
        int T = (i >> 9) & 3;
        int chunk = i >> 11;
        int col = 16 * T + (lane & 15);
        int k = chunk * 32 + 8 * (lane >> 4) + j;
        float w = W1[k * 64 + col];
        unsigned u = __float_as_uint(w);
        unsigned hu = u & 0xFFFF0000u;
        float rem = w - __uint_as_float(hu);
        bhi[i] = (unsigned short)(hu >> 16);
        blo[i] = (unsigned short)(__float_as_uint(rem) >> 16);
    } else {
        int b = blockIdx.x - 128;           // 0..511
        cnt[t] = 0; cnt[t + 256] = 0;
        __syncthreads();
        int i = b * 256 + t;
        int stride = 512 * 256;
        for (; i < E; i += stride) atomicAdd(&cnt[dst[i] >> BSHIFT], 1);
        __syncthreads();
        if (t < nbuck && cnt[t]) atomicAdd(&bucketCounts[t], cnt[t]);
        int t2 = t + 256;
        if (t2 < nbuck && cnt[t2]) atomicAdd(&bucketCounts[t2], cnt[t2]);
    }
}

__global__ __launch_bounds__(512) void bucket_scan_kernel(
    const int* __restrict__ bucketCounts, int* __restrict__ bucketBase,
    int* __restrict__ bucketCursor, int nbuck)
{
    __shared__ int wsum[8];
    int t = threadIdx.x, lane = t & 63, w = t >> 6;
    int c = (t < nbuck) ? bucketCounts[t] : 0;
    int inc = c;
    #pragma unroll
    for (int d = 1; d < 64; d <<= 1) {
        int u = __shfl_up(inc, d);
        if (lane >= d) inc += u;
    }
    if (lane == 63) wsum[w] = inc;
    __syncthreads();
    if (t == 0) { int run = 0; for (int k = 0; k < 8; ++k) { int tmp = wsum[k]; wsum[k] = run; run += tmp; } }
    __syncthreads();
    int excl = inc - c + wsum[w];
    if (t < nbuck) { bucketBase[t] = excl; bucketCursor[t] = excl; }
    if (t == nbuck) bucketBase[t] = excl;
}

// ---------------- fused: coarse scatter (blocks 0..nCoarse-1) || GEMM1 (rest)
// 32 rows/block: 2 row-groups share every B-fragment -> B line-traffic halves.
__global__ __launch_bounds__(256) void gemm1_coarse_kernel(
    const float* __restrict__ x,
    const unsigned short* __restrict__ bhi, const unsigned short* __restrict__ blo,
    const float* __restrict__ as1, const float* __restrict__ ad1,
    unsigned short* __restrict__ h1, float* __restrict__ asrc1, float* __restrict__ adst1,
    int n,
    const int* __restrict__ src, const int* __restrict__ dstv,
    int* __restrict__ bucketCursor, unsigned int* __restrict__ tmp, int E, int nCoarse)
{
    __shared__ float lds[4][32][68];   // 34.8 KB: per-wave k-half stage / partials; coarse cnt+gbase
    int t = threadIdx.x;

    if ((int)blockIdx.x < nCoarse) {
        int* cnt   = (int*)&lds[0][0][0];
        int* gbase = cnt + 512;
        cnt[t] = 0; cnt[t + 256] = 0;
        __syncthreads();
        int base = blockIdx.x * (256 * K3_EPT);
        unsigned int pk[K3_EPT];
        unsigned int meta[K3_EPT];
        #pragma unroll
        for (int j = 0; j < K3_EPT; ++j) {
            int i = base + t + j * 256;
            if (i < E) {
                int d = dstv[i], s = src[i];
                int b = d >> BSHIFT;
                pk[j] = ((unsigned)s << 16) | (unsigned)(d & BMASK);
                int r = atomicAdd(&cnt[b], 1);
                meta[j] = ((unsigned)r << 9) | (unsigned)b;
            } else {
                meta[j] = 0xFFFFFFFFu; pk[j] = 0;
            }
        }
        __syncthreads();
        if (cnt[t] > 0) gbase[t] = atomicAdd(&bucketCursor[t], cnt[t]);
        int t2 = t + 256;
        if (cnt[t2] > 0) gbase[t2] = atomicAdd(&bucketCursor[t2], cnt[t2]);
        __syncthreads();
        #pragma unroll
        for (int j = 0; j < K3_EPT; ++j) {
            if (meta[j] != 0xFFFFFFFFu) {
                int b = meta[j] & 511;
                int r = meta[j] >> 9;
                tmp[gbase[b] + r] = pk[j];
            }
        }
        return;
    }

    // ---- GEMM1 part: 32 rows, wave owns k-quarter, staged 64 k at a time ----
    int wave = t >> 6, l = t & 63;
    int il = l & 15, g = l >> 4;
    int r0 = (blockIdx.x - nCoarse) * 32;
    int kw = wave * 128;

    f32x4 acc[2][4] = {{{0.f,0.f,0.f,0.f},{0.f,0.f,0.f,0.f},{0.f,0.f,0.f,0.f},{0.f,0.f,0.f,0.f}},
                       {{0.f,0.f,0.f,0.f},{0.f,0.f,0.f,0.f},{0.f,0.f,0.f,0.f},{0.f,0.f,0.f,0.f}}};

    #pragma unroll
    for (int ph = 0; ph < 2; ++ph) {
        // stage 32 rows x 64 k: 8 float4 per lane, coalesced (4 rows x 256B per instr)
        #pragma unroll
        for (int j = 0; j < 8; ++j) {
            int idx = j * 64 + l;          // 0..511
            int row = idx >> 4;            // 32 rows
            int kq = idx & 15;             // float4 slot in 64-float slice
            int gr = r0 + row; if (gr >= n) gr = n - 1;
            float4 v = *(const float4*)(x + (size_t)gr * IN_DIM + kw + ph * 64 + kq * 4);
            *(float4*)(&lds[wave][row][kq * 4]) = v;
        }
        // wave-local buffer: compiler-inserted lgkm waits; no barrier
        #pragma unroll
        for (int itp = 0; itp < 2; ++itp) {
            int it = ph * 2 + itp;
            int chunk = wave * 4 + it;
            const short8b* bh = (const short8b*)bhi + (size_t)(chunk * 4) * 64 + l;
            const short8b* bl = (const short8b*)blo + (size_t)(chunk * 4) * 64 + l;
            short8b Bh[4], Bl[4];
            #pragma unroll
            for (int T = 0; T < 4; ++T) { Bh[T] = bh[T * 64]; Bl[T] = bl[T * 64]; }
            #pragma unroll
            for (int rg = 0; rg < 2; ++rg) {
                float av[8];
                *(float4*)(&av[0]) = *(const float4*)(&lds[wave][rg * 16 + il][32 * itp + 8 * g]);
                *(float4*)(&av[4]) = *(const float4*)(&lds[wave][rg * 16 + il][32 * itp + 8 * g + 4]);
                short8b Ahi, Alo;
                #pragma unroll
                for (int j = 0; j < 8; ++j) {
                    unsigned u = __float_as_uint(av[j]);
                    unsigned hu = u & 0xFFFF0000u;
                    float rem = av[j] - __uint_as_float(hu);
                    Ahi[j] = (short)(hu >> 16);
                    Alo[j] = (short)(__float_as_uint(rem) >> 16);
                }
                #pragma unroll
                for (int T = 0; T < 4; ++T) {
                    acc[rg][T] = __builtin_amdgcn_mfma_f32_16x16x32_bf16(Alo, Bh[T], acc[rg][T], 0, 0, 0);
                    acc[rg][T] = __builtin_amdgcn_mfma_f32_16x16x32_bf16(Ahi, Bl[T], acc[rg][T], 0, 0, 0);
                    acc[rg][T] = __builtin_amdgcn_mfma_f32_16x16x32_bf16(Ahi, Bh[T], acc[rg][T], 0, 0, 0);
                }
            }
        }
    }

    // partials -> LDS (rows 0..31, cols 0..63), cross-wave reduce
    #pragma unroll
    for (int rg = 0; rg < 2; ++rg)
        #pragma unroll
        for (int T = 0; T < 4; ++T)
            #pragma unroll
            for (int r = 0; r < 4; ++r)
                lds[wave][rg * 16 + 4 * g + r][16 * T + il] = acc[rg][T][r];
    __syncthreads();

    #pragma unroll
    for (int half = 0; half < 2; ++half) {
        int i = t + half * 256;            // 0..511 items: 32 rows x 16 col4-groups
        int row = i >> 4, c0 = (i & 15) * 4;
        int grow = r0 + row;
        float v0 = lds[0][row][c0]     + lds[1][row][c0]     + lds[2][row][c0]     + lds[3][row][c0];
        float v1 = lds[0][row][c0 + 1] + lds[1][row][c0 + 1] + lds[2][row][c0 + 1] + lds[3][row][c0 + 1];
        float v2 = lds[0][row][c0 + 2] + lds[1][row][c0 + 2] + lds[2][row][c0 + 2] + lds[3][row][c0 + 2];
        float v3 = lds[0][row][c0 + 3] + lds[1][row][c0 + 3] + lds[2][row][c0 + 3] + lds[3][row][c0 + 3];
        float4 asv = *(const float4*)(as1 + c0);
        float4 adv = *(const float4*)(ad1 + c0);
        float pa = v0 * asv.x + v1 * asv.y + v2 * asv.z + v3 * asv.w;
        float pd = v0 * adv.x + v1 * adv.y + v2 * adv.z + v3 * adv.w;
        pa += __shfl_xor(pa, 1);           // partner handles i^1: same row, paired col4
        pd += __shfl_xor(pd, 1);
        if (grow < n) {
            ushort4 hb;
            hb.x = f2bf_rne(v0); hb.y = f2bf_rne(v1);
            hb.z = f2bf_rne(v2); hb.w = f2bf_rne(v3);
            *(ushort4*)(h1 + (size_t)grow * 64 + c0) = hb;
            if ((t & 1) == 0) {
                int head = (i & 15) >> 1;
                asrc1[grow * 8 + head] = pa;
                adst1[grow * 8 + head] = pd;
            }
        }
    }
}

__global__ __launch_bounds__(256) void fine_scatter_kernel(
    const unsigned int* __restrict__ tmp, const int* __restrict__ bucketBase,
    int* __restrict__ csr, int* __restrict__ offsets, int* __restrict__ counts, int n)
{
    __shared__ int cnt[128];
    __shared__ int cur[128];
    __shared__ int wsum[2];
    int b = blockIdx.x;
    int t = threadIdx.x, lane = t & 63, w = t >> 6;
    int beg = bucketBase[b], end = bucketBase[b + 1];
    if (t < 128) cnt[t] = 0;
    __syncthreads();
    for (int i = beg + t; i < end; i += 256)
        atomicAdd(&cnt[tmp[i] & BMASK], 1);
    __syncthreads();
    if (t < 128) {
        int c = cnt[t];
        int inc = c;
        #pragma unroll
        for (int d = 1; d < 64; d <<= 1) {
            int u = __shfl_up(inc, d);
            if (lane >= d) inc += u;
        }
        if (lane == 63) wsum[w] = inc;
        __syncthreads();
        if (t == 0) { int r0_ = wsum[0]; wsum[0] = 0; wsum[1] = r0_; }
        __syncthreads();
        int excl = inc - c + wsum[w];
        int node = b * 128 + t;
        if (node < n) { offsets[node] = beg + excl; counts[node] = c; }
        cur[t] = excl;
    } else {
        __syncthreads(); __syncthreads();
    }
    __syncthreads();
    for (int i = beg + t; i < end; i += 256) {
        unsigned int p = tmp[i];
        int r = atomicAdd(&cur[p & BMASK], 1);
        csr[beg + r] = (int)(p >> 16);
    }
}

// ---------------- Layer-1 edge kernel: single-pass, bf16 h1 gathers --------
__global__ __launch_bounds__(256) void l1_edge_kernel(
    const int* __restrict__ offsets, const int* __restrict__ counts,
    const int* __restrict__ csr,
    const float* __restrict__ asrc1, const float* __restrict__ adst1,
    const unsigned short* __restrict__ h1, const float* __restrict__ b1,
    const float* __restrict__ W2, const float* __restrict__ as2,
    const float* __restrict__ ad2,
    float* __restrict__ h2, float* __restrict__ asrc2, float* __restrict__ adst2,
    int n)
{
    __shared__ float w2t[8][64];
    __shared__ float s_as2[8], s_ad2[8], s_b1[64];
    __shared__ int csr_s[4][64];
    int t = threadIdx.x;
    if (t < 64) {
        #pragma unroll
        for (int j = 0; j < OUT_DIM; ++j) w2t[j][t] = W2[t * OUT_DIM + j];
        s_b1[t] = b1[t];
        if (t < OUT_DIM) { s_as2[t] = as2[t]; s_ad2[t] = ad2[t]; }
    }
    __syncthreads();

    int lane = t & 63;
    int nl = t >> 6;
    int node = blockIdx.x * 4 + nl;
    if (node >= n) return;
    int beg = offsets[node];
    int deg = counts[node];
    int q = lane >> 4;
    int il = lane & 15;
    int c0 = il * 4;
    int head = il >> 1;
    float adv = adst1[node * 8 + head];

    if (lane < deg) csr_s[nl][lane] = csr[beg + lane];
    int deg_r = deg < 64 ? deg : 64;
    const int* cs = &csr_s[nl][0];

    float4 acc = make_float4(0.f, 0.f, 0.f, 0.f);
    float ssum = 0.f;
    if (q == 0) {   // self loop
        float e = asrc1[node * 8 + head] + adv;
        e = e > 0.f ? e : NEG_SLOPE * e;
        float p = __expf(e);
        ushort4 hu = *(const ushort4*)(h1 + (size_t)node * 64 + c0);
        acc.x = p * bf2f(hu.x); acc.y = p * bf2f(hu.y);
        acc.z = p * bf2f(hu.z); acc.w = p * bf2f(hu.w);
        ssum = p;
    }
    int j = q;
    for (; j + 12 < deg_r; j += 16) {
        int s0 = cs[j];
        int s1 = cs[j + 4];
        int s2 = cs[j + 8];
        int s3 = cs[j + 12];
        float a0 = asrc1[s0 * 8 + head], a1 = asrc1[s1 * 8 + head];
        float a2 = asrc1[s2 * 8 + head], a3 = asrc1[s3 * 8 + head];
        ushort4 g0 = *(const ushort4*)(h1 + (size_t)s0 * 64 + c0);
        ushort4 g1 = *(const ushort4*)(h1 + (size_t)s1 * 64 + c0);
        ushort4 g2 = *(const ushort4*)(h1 + (size_t)s2 * 64 + c0);
        ushort4 g3 = *(const ushort4*)(h1 + (size_t)s3 * 64 + c0);
        float e0 = a0 + adv; e0 = e0 > 0.f ? e0 : NEG_SLOPE * e0;
        float e1 = a1 + adv; e1 = e1 > 0.f ? e1 : NEG_SLOPE * e1;
        float e2 = a2 + adv; e2 = e2 > 0.f ? e2 : NEG_SLOPE * e2;
        float e3 = a3 + adv; e3 = e3 > 0.f ? e3 : NEG_SLOPE * e3;
        float p0 = __expf(e0), p1 = __expf(e1);
        float p2 = __expf(e2), p3 = __expf(e3);
        acc.x = fmaf(p0, bf2f(g0.x), acc.x); acc.y = fmaf(p0, bf2f(g0.y), acc.y);
        acc.z = fmaf(p0, bf2f(g0.z), acc.z); acc.w = fmaf(p0, bf2f(g0.w), acc.w);
        acc.x = fmaf(p1, bf2f(g1.x), acc.x); acc.y = fmaf(p1, bf2f(g1.y), acc.y);
        acc.z = fmaf(p1, bf2f(g1.z), acc.z); acc.w = fmaf(p1, bf2f(g1.w), acc.w);
        acc.x = fmaf(p2, bf2f(g2.x), acc.x); acc.y = fmaf(p2, bf2f(g2.y), acc.y);
        acc.z = fmaf(p2, bf2f(g2.z), acc.z); acc.w = fmaf(p2, bf2f(g2.w), acc.w);
        acc.x = fmaf(p3, bf2f(g3.x), acc.x); acc.y = fmaf(p3, bf2f(g3.y), acc.y);
        acc.z = fmaf(p3, bf2f(g3.z), acc.z); acc.w = fmaf(p3, bf2f(g3.w), acc.w);
        ssum += (p0 + p1) + (p2 + p3);
    }
    for (; j < deg_r; j += 4) {
        int sn = cs[j];
        float a = asrc1[sn * 8 + head];
        ushort4 g = *(const ushort4*)(h1 + (size_t)sn * 64 + c0);
        float e = a + adv; e = e > 0.f ? e : NEG_SLOPE * e;
        float p = __expf(e);
        acc.x = fmaf(p, bf2f(g.x), acc.x); acc.y = fmaf(p, bf2f(g.y), acc.y);
        acc.z = fmaf(p, bf2f(g.z), acc.z); acc.w = fmaf(p, bf2f(g.w), acc.w);
        ssum += p;
    }
    for (; j < deg; j += 4) {
        int sn = csr[beg + j];
        float a = asrc1[sn * 8 + head];
        ushort4 g = *(const ushort4*)(h1 + (size_t)sn * 64 + c0);
        float e = a + adv; e = e > 0.f ? e : NEG_SLOPE * e;
        float p = __expf(e);
        acc.x = fmaf(p, bf2f(g.x), acc.x); acc.y = fmaf(p, bf2f(g.y), acc.y);
        acc.z = fmaf(p, bf2f(g.z), acc.z); acc.w = fmaf(p, bf2f(g.w), acc.w);
        ssum += p;
    }
    acc.x += __shfl_xor(acc.x, 16); acc.x += __shfl_xor(acc.x, 32);
    acc.y += __shfl_xor(acc.y, 16); acc.y += __shfl_xor(acc.y, 32);
    acc.z += __shfl_xor(acc.z, 16); acc.z += __shfl_xor(acc.z, 32);
    acc.w += __shfl_xor(acc.w, 16); acc.w += __shfl_xor(acc.w, 32);
    ssum  += __shfl_xor(ssum, 16);  ssum  += __shfl_xor(ssum, 32);
    float inv = 1.f / fmaxf(ssum, 1e-16f);

    float4 bv = *(const float4*)(&s_b1[c0]);
    float v0 = acc.x * inv + bv.x;
    float v1 = acc.y * inv + bv.y;
    float v2 = acc.z * inv + bv.z;
    float v3 = acc.w * inv + bv.w;
    v0 = v0 > 0.f ? v0 : __expf(v0) - 1.f;
    v1 = v1 > 0.f ? v1 : __expf(v1) - 1.f;
    v2 = v2 > 0.f ? v2 : __expf(v2) - 1.f;
    v3 = v3 > 0.f ? v3 : __expf(v3) - 1.f;

    float hj[OUT_DIM];
    #pragma unroll
    for (int jj = 0; jj < OUT_DIM; ++jj) {
        float4 wv = *(const float4*)(&w2t[jj][c0]);
        float p = v0 * wv.x + v1 * wv.y + v2 * wv.z + v3 * wv.w;
        p += __shfl_xor(p, 1);
        p += __shfl_xor(p, 2);
        p += __shfl_xor(p, 4);
        p += __shfl_xor(p, 8);
        hj[jj] = p;
    }
    float a_s = 0.f, a_d = 0.f;
    #pragma unroll
    for (int jj = 0; jj < OUT_DIM; ++jj) { a_s += hj[jj] * s_as2[jj]; a_d += hj[jj] * s_ad2[jj]; }
    if (lane < 8) h2[node * 8 + lane] = (lane < OUT_DIM) ? hj[lane] : 0.f;
    if (lane == 0) { asrc2[node] = a_s; adst2[node] = a_d; }
}

// ---------------- Layer-2 edge kernel: single-pass -> final logits --------
__global__ __launch_bounds__(256) void l2_edge_kernel(
    const int* __restrict__ offsets, const int* __restrict__ counts,
    const int* __restrict__ csr,
    const float* __restrict__ asrc2, const float* __restrict__ adst2,
    const float* __restrict__ h2, const float* __restrict__ b2,
    float* __restrict__ out, int n)
{
    int t = threadIdx.x, lane = t & 63;
    int node = blockIdx.x * 4 + (t >> 6);
    if (node >= n) return;
    int beg = offsets[node];
    int deg = counts[node];
    float adv = adst2[node];

    int c = lane & 7, slot = lane >> 3;
    float acc = 0.f, ssum = 0.f;
    if (slot == 0) {
        float e = asrc2[node] + adv;
        e = e > 0.f ? e : NEG_SLOPE * e;
        float p = __expf(e);
        acc = p * h2[node * 8 + c];
        ssum = p;
    }
    int j = slot;
    for (; j + 8 < deg; j += 16) {
        int s0 = csr[beg + j], s1 = csr[beg + j + 8];
        float a0 = asrc2[s0], a1 = asrc2[s1];
        float g0 = h2[s0 * 8 + c], g1 = h2[s1 * 8 + c];
        float e0 = a0 + adv; e0 = e0 > 0.f ? e0 : NEG_SLOPE * e0;
        float e1 = a1 + adv; e1 = e1 > 0.f ? e1 : NEG_SLOPE * e1;
        float p0 = __expf(e0), p1 = __expf(e1);
        acc = fmaf(p0, g0, acc); acc = fmaf(p1, g1, acc);
        ssum += p0 + p1;
    }
    for (; j < deg; j += 8) {
        int sn = csr[beg + j];
        float e = asrc2[sn] + adv;
        e = e > 0.f ? e : NEG_SLOPE * e;
        float p = __expf(e);
        acc = fmaf(p, h2[sn * 8 + c], acc);
        ssum += p;
    }
    acc  += __shfl_xor(acc, 8);  acc  += __shfl_xor(acc, 16);  acc  += __shfl_xor(acc, 32);
    ssum += __shfl_xor(ssum, 8); ssum += __shfl_xor(ssum, 16); ssum += __shfl_xor(ssum, 32);
    float inv = 1.f / fmaxf(ssum, 1e-16f);
    if (lane < OUT_DIM) out[(size_t)node * OUT_DIM + lane] = acc * inv + b2[lane];
}

// ---------------- launch ----------------
static inline size_t rup256(size_t x) { return (x + 255) & ~(size_t)255; }

extern "C" void kernel_launch(void* const* d_in, const int* in_sizes, int n_in,
                              void* d_out, int out_size, void* d_ws, size_t ws_size,
                              hipStream_t stream)
{
    int n = in_sizes[0] / IN_DIM;       // 50000
    int E = in_sizes[1] / 2;            // 1600000
    int nbuck = (n + BMASK) >> BSHIFT;  // 391
    int nCoarse = (E + 256 * K3_EPT - 1) / (256 * K3_EPT);   // 391

    const float* x   = (const float*)d_in[0];
    const int*   ei  = (const int*)d_in[1];
    const int*   srcv = ei;
    const int*   dstv = ei + E;
    const float* W1  = (const float*)d_in[2];
    const float* as1 = (const float*)d_in[3];
    const float* ad1 = (const float*)d_in[4];
    const float* b1  = (const float*)d_in[5];
    const float* W2  = (const float*)d_in[6];
    const float* as2 = (const float*)d_in[7];
    const float* ad2 = (const float*)d_in[8];
    const float* b2  = (const float*)d_in[9];
    float* out = (float*)d_out;

    char* p = (char*)d_ws;
    auto alloc = [&](size_t bytes) { char* q = p; p += rup256(bytes); return (void*)q; };
    unsigned short* h1 = (unsigned short*)alloc((size_t)n * 64 * 2);
    float* asrc1   = (float*)alloc((size_t)n * 8 * 4);
    float* adst1   = (float*)alloc((size_t)n * 8 * 4);
    float* h2      = (float*)alloc((size_t)n * 8 * 4);
    float* asrc2   = (float*)alloc((size_t)n * 4);
    float* adst2   = (float*)alloc((size_t)n * 4);
    int*   counts  = (int*)alloc((size_t)n * 4);
    int*   offsets = (int*)alloc(((size_t)n + 1) * 4);
    int*   csr     = (int*)alloc((size_t)E * 4);
    unsigned int* tmp = (unsigned int*)alloc((size_t)E * 4);
    int*   bucketCounts = (int*)alloc(512 * 4);
    int*   bucketBase   = (int*)alloc(513 * 4);
    int*   bucketCursor = (int*)alloc(512 * 4);
    unsigned short* bhi = (unsigned short*)alloc((size_t)IN_DIM * 64 * 2);
    unsigned short* blo = (unsigned short*)alloc((size_t)IN_DIM * 64 * 2);

    hipMemsetAsync(bucketCounts, 0, 512 * 4, stream);
    prep_kernel<<<128 + 512, 256, 0, stream>>>(W1, bhi, blo, dstv, bucketCounts, E, nbuck);
    bucket_scan_kernel<<<1, 512, 0, stream>>>(bucketCounts, bucketBase, bucketCursor, nbuck);
    gemm1_coarse_kernel<<<nCoarse + (n + 31) / 32, 256, 0, stream>>>(
        x, bhi, blo, as1, ad1, h1, asrc1, adst1, n,
        srcv, dstv, bucketCursor, tmp, E, nCoarse);
    fine_scatter_kernel<<<nbuck, 256, 0, stream>>>(
        tmp, bucketBase, csr, offsets, counts, n);
    l1_edge_kernel<<<(n + 3) / 4, 256, 0, stream>>>(
        offsets, counts, csr, asrc1, adst1, h1, b1, W2, as2, ad2, h2, asrc2, adst2, n);
    l2_edge_kernel<<<(n + 3) / 4, 256, 0, stream>>>(
        offsets, counts, csr, asrc2, adst2, h2, b2, out, n);
}

// Round 20
// 143.066 us; speedup vs baseline: 1.0084x; 1.0048x over previous
//
#include <hip/hip_runtime.h>
#include <hip/hip_bf16.h>

#define IN_DIM 512
#define HEADS 8
#define HID 8
#define OUT_DIM 7
#define NEG_SLOPE 0.2f

typedef __attribute__((ext_vector_type(8))) short short8b;   // 8 bf16 (4 VGPR)
typedef __attribute__((ext_vector_type(4))) float f32x4;

#define BSHIFT 7
#define BMASK 127
#define K3_EPT 16

__device__ __forceinline__ unsigned short f2bf_rne(float f) {
    unsigned u = __float_as_uint(f);
    unsigned r = (u + 0x7FFFu + ((u >> 16) & 1u)) >> 16;
    return (unsigned short)r;
}
__device__ __forceinline__ float bf2f(unsigned short s) {
    return __uint_as_float((unsigned)s << 16);
}

// ---------------- prep: W1 fragment-pack (blocks 0..127) || bucket hist (128..639)
__global__ __launch_bounds__(256) void prep_kernel(
    const float* __restrict__ W1, unsigned short* __restrict__ bhi,
    unsigned short* __restrict__ blo,
    const int* __restrict__ dst, int* __restrict__ bucketCounts, int E, int nbuck)
{
    __shared__ int cnt[512];
    int t = threadIdx.x;
    if (blockIdx.x < 128) {
        int i = blockIdx.x * 256 + t;       // 0..32767
        int j = i & 7;
        int lane = (i >> 3) & 63;
        int T = (i >> 9) & 3;
        int chunk = i >> 11;
        int col = 16 * T + (lane & 15);
        int k = chunk * 32 + 8 * (lane >> 4) + j;
        float w = W1[k * 64 + col];
        unsigned u = __float_as_uint(w);
        unsigned hu = u & 0xFFFF0000u;
        float rem = w - __uint_as_float(hu);
        bhi[i] = (unsigned short)(hu >> 16);
        blo[i] = (unsigned short)(__float_as_uint(rem) >> 16);
    } else {
        int b = blockIdx.x - 128;           // 0..511
        cnt[t] = 0; cnt[t + 256] = 0;
        __syncthreads();
        int i = b * 256 + t;
        int stride = 512 * 256;
        for (; i < E; i += stride) atomicAdd(&cnt[dst[i] >> BSHIFT], 1);
        __syncthreads();
        if (t < nbuck && cnt[t]) atomicAdd(&bucketCounts[t], cnt[t]);
        int t2 = t + 256;
        if (t2 < nbuck && cnt[t2]) atomicAdd(&bucketCounts[t2], cnt[t2]);
    }
}

__global__ __launch_bounds__(512) void bucket_scan_kernel(
    const int* __restrict__ bucketCounts, int* __restrict__ bucketBase,
    int* __restrict__ bucketCursor, int nbuck)
{
    __shared__ int wsum[8];
    int t = threadIdx.x, lane = t & 63, w = t >> 6;
    int c = (t < nbuck) ? bucketCounts[t] : 0;
    int inc = c;
    #pragma unroll
    for (int d = 1; d < 64; d <<= 1) {
        int u = __shfl_up(inc, d);
        if (lane >= d) inc += u;
    }
    if (lane == 63) wsum[w] = inc;
    __syncthreads();
    if (t == 0) { int run = 0; for (int k = 0; k < 8; ++k) { int tmp = wsum[k]; wsum[k] = run; run += tmp; } }
    __syncthreads();
    int excl = inc - c + wsum[w];
    if (t < nbuck) { bucketBase[t] = excl; bucketCursor[t] = excl; }
    if (t == nbuck) bucketBase[t] = excl;
}

// ---------------- fused: GEMM1 (blocks 0..nGemm-1, scheduled FIRST) ||
//                  coarse scatter (last nCoarse blocks, rides gemm1's idle slots)
__global__ __launch_bounds__(256) void gemm1_coarse_kernel(
    const float* __restrict__ x,
    const unsigned short* __restrict__ bhi, const unsigned short* __restrict__ blo,
    const float* __restrict__ as1, const float* __restrict__ ad1,
    unsigned short* __restrict__ h1, float* __restrict__ asrc1, float* __restrict__ adst1,
    int n,
    const int* __restrict__ src, const int* __restrict__ dstv,
    int* __restrict__ bucketCursor, unsigned int* __restrict__ tmp, int E, int nGemm)
{
    __shared__ float lds[4][32][68];   // 34.8 KB: per-wave k-half stage / partials; coarse cnt+gbase
    int t = threadIdx.x;

    if ((int)blockIdx.x >= nGemm) {
        // ---- coarse scatter part (last blocks) ----
        int* cnt   = (int*)&lds[0][0][0];
        int* gbase = cnt + 512;
        cnt[t] = 0; cnt[t + 256] = 0;
        __syncthreads();
        int base = (blockIdx.x - nGemm) * (256 * K3_EPT);
        unsigned int pk[K3_EPT];
        unsigned int meta[K3_EPT];
        #pragma unroll
        for (int j = 0; j < K3_EPT; ++j) {
            int i = base + t + j * 256;
            if (i < E) {
                int d = dstv[i], s = src[i];
                int b = d >> BSHIFT;
                pk[j] = ((unsigned)s << 16) | (unsigned)(d & BMASK);
                int r = atomicAdd(&cnt[b], 1);
                meta[j] = ((unsigned)r << 9) | (unsigned)b;
            } else {
                meta[j] = 0xFFFFFFFFu; pk[j] = 0;
            }
        }
        __syncthreads();
        if (cnt[t] > 0) gbase[t] = atomicAdd(&bucketCursor[t], cnt[t]);
        int t2 = t + 256;
        if (cnt[t2] > 0) gbase[t2] = atomicAdd(&bucketCursor[t2], cnt[t2]);
        __syncthreads();
        #pragma unroll
        for (int j = 0; j < K3_EPT; ++j) {
            if (meta[j] != 0xFFFFFFFFu) {
                int b = meta[j] & 511;
                int r = meta[j] >> 9;
                tmp[gbase[b] + r] = pk[j];
            }
        }
        return;
    }

    // ---- GEMM1 part: 32 rows, wave owns k-quarter, staged 64 k at a time ----
    int wave = t >> 6, l = t & 63;
    int il = l & 15, g = l >> 4;
    int r0 = blockIdx.x * 32;
    int kw = wave * 128;

    f32x4 acc[2][4] = {{{0.f,0.f,0.f,0.f},{0.f,0.f,0.f,0.f},{0.f,0.f,0.f,0.f},{0.f,0.f,0.f,0.f}},
                       {{0.f,0.f,0.f,0.f},{0.f,0.f,0.f,0.f},{0.f,0.f,0.f,0.f},{0.f,0.f,0.f,0.f}}};

    #pragma unroll
    for (int ph = 0; ph < 2; ++ph) {
        // stage 32 rows x 64 k: 8 float4 per lane, coalesced (4 rows x 256B per instr)
        #pragma unroll
        for (int j = 0; j < 8; ++j) {
            int idx = j * 64 + l;          // 0..511
            int row = idx >> 4;            // 32 rows
            int kq = idx & 15;             // float4 slot in 64-float slice
            int gr = r0 + row; if (gr >= n) gr = n - 1;
            float4 v = *(const float4*)(x + (size_t)gr * IN_DIM + kw + ph * 64 + kq * 4);
            *(float4*)(&lds[wave][row][kq * 4]) = v;
        }
        // wave-local buffer: compiler-inserted lgkm waits; no barrier
        #pragma unroll
        for (int itp = 0; itp < 2; ++itp) {
            int it = ph * 2 + itp;
            int chunk = wave * 4 + it;
            const short8b* bh = (const short8b*)bhi + (size_t)(chunk * 4) * 64 + l;
            const short8b* bl = (const short8b*)blo + (size_t)(chunk * 4) * 64 + l;
            short8b Bh[4], Bl[4];
            #pragma unroll
            for (int T = 0; T < 4; ++T) { Bh[T] = bh[T * 64]; Bl[T] = bl[T * 64]; }
            #pragma unroll
            for (int rg = 0; rg < 2; ++rg) {
                float av[8];
                *(float4*)(&av[0]) = *(const float4*)(&lds[wave][rg * 16 + il][32 * itp + 8 * g]);
                *(float4*)(&av[4]) = *(const float4*)(&lds[wave][rg * 16 + il][32 * itp + 8 * g + 4]);
                short8b Ahi, Alo;
                #pragma unroll
                for (int j = 0; j < 8; ++j) {
                    unsigned u = __float_as_uint(av[j]);
                    unsigned hu = u & 0xFFFF0000u;
                    float rem = av[j] - __uint_as_float(hu);
                    Ahi[j] = (short)(hu >> 16);
                    Alo[j] = (short)(__float_as_uint(rem) >> 16);
                }
                #pragma unroll
                for (int T = 0; T < 4; ++T) {
                    acc[rg][T] = __builtin_amdgcn_mfma_f32_16x16x32_bf16(Alo, Bh[T], acc[rg][T], 0, 0, 0);
                    acc[rg][T] = __builtin_amdgcn_mfma_f32_16x16x32_bf16(Ahi, Bl[T], acc[rg][T], 0, 0, 0);
                    acc[rg][T] = __builtin_amdgcn_mfma_f32_16x16x32_bf16(Ahi, Bh[T], acc[rg][T], 0, 0, 0);
                }
            }
        }
    }

    // partials -> LDS (rows 0..31, cols 0..63), cross-wave reduce
    #pragma unroll
    for (int rg = 0; rg < 2; ++rg)
        #pragma unroll
        for (int T = 0; T < 4; ++T)
            #pragma unroll
            for (int r = 0; r < 4; ++r)
                lds[wave][rg * 16 + 4 * g + r][16 * T + il] = acc[rg][T][r];
    __syncthreads();

    #pragma unroll
    for (int half = 0; half < 2; ++half) {
        int i = t + half * 256;            // 0..511 items: 32 rows x 16 col4-groups
        int row = i >> 4, c0 = (i & 15) * 4;
        int grow = r0 + row;
        float v0 = lds[0][row][c0]     + lds[1][row][c0]     + lds[2][row][c0]     + lds[3][row][c0];
        float v1 = lds[0][row][c0 + 1] + lds[1][row][c0 + 1] + lds[2][row][c0 + 1] + lds[3][row][c0 + 1];
        float v2 = lds[0][row][c0 + 2] + lds[1][row][c0 + 2] + lds[2][row][c0 + 2] + lds[3][row][c0 + 2];
        float v3 = lds[0][row][c0 + 3] + lds[1][row][c0 + 3] + lds[2][row][c0 + 3] + lds[3][row][c0 + 3];
        float4 asv = *(const float4*)(as1 + c0);
        float4 adv = *(const float4*)(ad1 + c0);
        float pa = v0 * asv.x + v1 * asv.y + v2 * asv.z + v3 * asv.w;
        float pd = v0 * adv.x + v1 * adv.y + v2 * adv.z + v3 * adv.w;
        pa += __shfl_xor(pa, 1);           // partner handles i^1: same row, paired col4
        pd += __shfl_xor(pd, 1);
        if (grow < n) {
            ushort4 hb;
            hb.x = f2bf_rne(v0); hb.y = f2bf_rne(v1);
            hb.z = f2bf_rne(v2); hb.w = f2bf_rne(v3);
            *(ushort4*)(h1 + (size_t)grow * 64 + c0) = hb;
            if ((t & 1) == 0) {
                int head = (i & 15) >> 1;
                asrc1[grow * 8 + head] = pa;
                adst1[grow * 8 + head] = pd;
            }
        }
    }
}

__global__ __launch_bounds__(256) void fine_scatter_kernel(
    const unsigned int* __restrict__ tmp, const int* __restrict__ bucketBase,
    int* __restrict__ csr, int* __restrict__ offsets, int* __restrict__ counts, int n)
{
    __shared__ int cnt[128];
    __shared__ int cur[128];
    __shared__ int wsum[2];
    int b = blockIdx.x;
    int t = threadIdx.x, lane = t & 63, w = t >> 6;
    int beg = bucketBase[b], end = bucketBase[b + 1];
    if (t < 128) cnt[t] = 0;
    __syncthreads();
    for (int i = beg + t; i < end; i += 256)
        atomicAdd(&cnt[tmp[i] & BMASK], 1);
    __syncthreads();
    if (t < 128) {
        int c = cnt[t];
        int inc = c;
        #pragma unroll
        for (int d = 1; d < 64; d <<= 1) {
            int u = __shfl_up(inc, d);
            if (lane >= d) inc += u;
        }
        if (lane == 63) wsum[w] = inc;
        __syncthreads();
        if (t == 0) { int r0_ = wsum[0]; wsum[0] = 0; wsum[1] = r0_; }
        __syncthreads();
        int excl = inc - c + wsum[w];
        int node = b * 128 + t;
        if (node < n) { offsets[node] = beg + excl; counts[node] = c; }
        cur[t] = excl;
    } else {
        __syncthreads(); __syncthreads();
    }
    __syncthreads();
    for (int i = beg + t; i < end; i += 256) {
        unsigned int p = tmp[i];
        int r = atomicAdd(&cur[p & BMASK], 1);
        csr[beg + r] = (int)(p >> 16);
    }
}

// ---------------- Layer-1 edge kernel: single-pass, bf16 h1 gathers --------
__global__ __launch_bounds__(256) void l1_edge_kernel(
    const int* __restrict__ offsets, const int* __restrict__ counts,
    const int* __restrict__ csr,
    const float* __restrict__ asrc1, const float* __restrict__ adst1,
    const unsigned short* __restrict__ h1, const float* __restrict__ b1,
    const float* __restrict__ W2, const float* __restrict__ as2,
    const float* __restrict__ ad2,
    float* __restrict__ h2, float* __restrict__ asrc2, float* __restrict__ adst2,
    int n)
{
    __shared__ float w2t[8][64];
    __shared__ float s_as2[8], s_ad2[8], s_b1[64];
    __shared__ int csr_s[4][64];
    int t = threadIdx.x;
    if (t < 64) {
        #pragma unroll
        for (int j = 0; j < OUT_DIM; ++j) w2t[j][t] = W2[t * OUT_DIM + j];
        s_b1[t] = b1[t];
        if (t < OUT_DIM) { s_as2[t] = as2[t]; s_ad2[t] = ad2[t]; }
    }
    __syncthreads();

    int lane = t & 63;
    int nl = t >> 6;
    int node = blockIdx.x * 4 + nl;
    if (node >= n) return;
    int beg = offsets[node];
    int deg = counts[node];
    int q = lane >> 4;
    int il = lane & 15;
    int c0 = il * 4;
    int head = il >> 1;
    float adv = adst1[node * 8 + head];

    if (lane < deg) csr_s[nl][lane] = csr[beg + lane];
    int deg_r = deg < 64 ? deg : 64;
    const int* cs = &csr_s[nl][0];

    float4 acc = make_float4(0.f, 0.f, 0.f, 0.f);
    float ssum = 0.f;
    if (q == 0) {   // self loop
        float e = asrc1[node * 8 + head] + adv;
        e = e > 0.f ? e : NEG_SLOPE * e;
        float p = __expf(e);
        ushort4 hu = *(const ushort4*)(h1 + (size_t)node * 64 + c0);
        acc.x = p * bf2f(hu.x); acc.y = p * bf2f(hu.y);
        acc.z = p * bf2f(hu.z); acc.w = p * bf2f(hu.w);
        ssum = p;
    }
    int j = q;
    for (; j + 12 < deg_r; j += 16) {
        int s0 = cs[j];
        int s1 = cs[j + 4];
        int s2 = cs[j + 8];
        int s3 = cs[j + 12];
        float a0 = asrc1[s0 * 8 + head], a1 = asrc1[s1 * 8 + head];
        float a2 = asrc1[s2 * 8 + head], a3 = asrc1[s3 * 8 + head];
        ushort4 g0 = *(const ushort4*)(h1 + (size_t)s0 * 64 + c0);
        ushort4 g1 = *(const ushort4*)(h1 + (size_t)s1 * 64 + c0);
        ushort4 g2 = *(const ushort4*)(h1 + (size_t)s2 * 64 + c0);
        ushort4 g3 = *(const ushort4*)(h1 + (size_t)s3 * 64 + c0);
        float e0 = a0 + adv; e0 = e0 > 0.f ? e0 : NEG_SLOPE * e0;
        float e1 = a1 + adv; e1 = e1 > 0.f ? e1 : NEG_SLOPE * e1;
        float e2 = a2 + adv; e2 = e2 > 0.f ? e2 : NEG_SLOPE * e2;
        float e3 = a3 + adv; e3 = e3 > 0.f ? e3 : NEG_SLOPE * e3;
        float p0 = __expf(e0), p1 = __expf(e1);
        float p2 = __expf(e2), p3 = __expf(e3);
        acc.x = fmaf(p0, bf2f(g0.x), acc.x); acc.y = fmaf(p0, bf2f(g0.y), acc.y);
        acc.z = fmaf(p0, bf2f(g0.z), acc.z); acc.w = fmaf(p0, bf2f(g0.w), acc.w);
        acc.x = fmaf(p1, bf2f(g1.x), acc.x); acc.y = fmaf(p1, bf2f(g1.y), acc.y);
        acc.z = fmaf(p1, bf2f(g1.z), acc.z); acc.w = fmaf(p1, bf2f(g1.w), acc.w);
        acc.x = fmaf(p2, bf2f(g2.x), acc.x); acc.y = fmaf(p2, bf2f(g2.y), acc.y);
        acc.z = fmaf(p2, bf2f(g2.z), acc.z); acc.w = fmaf(p2, bf2f(g2.w), acc.w);
        acc.x = fmaf(p3, bf2f(g3.x), acc.x); acc.y = fmaf(p3, bf2f(g3.y), acc.y);
        acc.z = fmaf(p3, bf2f(g3.z), acc.z); acc.w = fmaf(p3, bf2f(g3.w), acc.w);
        ssum += (p0 + p1) + (p2 + p3);
    }
    for (; j < deg_r; j += 4) {
        int sn = cs[j];
        float a = asrc1[sn * 8 + head];
        ushort4 g = *(const ushort4*)(h1 + (size_t)sn * 64 + c0);
        float e = a + adv; e = e > 0.f ? e : NEG_SLOPE * e;
        float p = __expf(e);
        acc.x = fmaf(p, bf2f(g.x), acc.x); acc.y = fmaf(p, bf2f(g.y), acc.y);
        acc.z = fmaf(p, bf2f(g.z), acc.z); acc.w = fmaf(p, bf2f(g.w), acc.w);
        ssum += p;
    }
    for (; j < deg; j += 4) {
        int sn = csr[beg + j];
        float a = asrc1[sn * 8 + head];
        ushort4 g = *(const ushort4*)(h1 + (size_t)sn * 64 + c0);
        float e = a + adv; e = e > 0.f ? e : NEG_SLOPE * e;
        float p = __expf(e);
        acc.x = fmaf(p, bf2f(g.x), acc.x); acc.y = fmaf(p, bf2f(g.y), acc.y);
        acc.z = fmaf(p, bf2f(g.z), acc.z); acc.w = fmaf(p, bf2f(g.w), acc.w);
        ssum += p;
    }
    acc.x += __shfl_xor(acc.x, 16); acc.x += __shfl_xor(acc.x, 32);
    acc.y += __shfl_xor(acc.y, 16); acc.y += __shfl_xor(acc.y, 32);
    acc.z += __shfl_xor(acc.z, 16); acc.z += __shfl_xor(acc.z, 32);
    acc.w += __shfl_xor(acc.w, 16); acc.w += __shfl_xor(acc.w, 32);
    ssum  += __shfl_xor(ssum, 16);  ssum  += __shfl_xor(ssum, 32);
    float inv = 1.f / fmaxf(ssum, 1e-16f);

    float4 bv = *(const float4*)(&s_b1[c0]);
    float v0 = acc.x * inv + bv.x;
    float v1 = acc.y * inv + bv.y;
    float v2 = acc.z * inv + bv.z;
    float v3 = acc.w * inv + bv.w;
    v0 = v0 > 0.f ? v0 : __expf(v0) - 1.f;
    v1 = v1 > 0.f ? v1 : __expf(v1) - 1.f;
    v2 = v2 > 0.f ? v2 : __expf(v2) - 1.f;
    v3 = v3 > 0.f ? v3 : __expf(v3) - 1.f;

    float hj[OUT_DIM];
    #pragma unroll
    for (int jj = 0; jj < OUT_DIM; ++jj) {
        float4 wv = *(const float4*)(&w2t[jj][c0]);
        float p = v0 * wv.x + v1 * wv.y + v2 * wv.z + v3 * wv.w;
        p += __shfl_xor(p, 1);
        p += __shfl_xor(p, 2);
        p += __shfl_xor(p, 4);
        p += __shfl_xor(p, 8);
        hj[jj] = p;
    }
    float a_s = 0.f, a_d = 0.f;
    #pragma unroll
    for (int jj = 0; jj < OUT_DIM; ++jj) { a_s += hj[jj] * s_as2[jj]; a_d += hj[jj] * s_ad2[jj]; }
    if (lane < 8) h2[node * 8 + lane] = (lane < OUT_DIM) ? hj[lane] : 0.f;
    if (lane == 0) { asrc2[node] = a_s; adst2[node] = a_d; }
}

// ---------------- Layer-2 edge kernel: single-pass -> final logits --------
__global__ __launch_bounds__(256) void l2_edge_kernel(
    const int* __restrict__ offsets, const int* __restrict__ counts,
    const int* __restrict__ csr,
    const float* __restrict__ asrc2, const float* __restrict__ adst2,
    const float* __restrict__ h2, const float* __restrict__ b2,
    float* __restrict__ out, int n)
{
    int t = threadIdx.x, lane = t & 63;
    int node = blockIdx.x * 4 + (t >> 6);
    if (node >= n) return;
    int beg = offsets[node];
    int deg = counts[node];
    float adv = adst2[node];

    int c = lane & 7, slot = lane >> 3;
    float acc = 0.f, ssum = 0.f;
    if (slot == 0) {
        float e = asrc2[node] + adv;
        e = e > 0.f ? e : NEG_SLOPE * e;
        float p = __expf(e);
        acc = p * h2[node * 8 + c];
        ssum = p;
    }
    int j = slot;
    for (; j + 8 < deg; j += 16) {
        int s0 = csr[beg + j], s1 = csr[beg + j + 8];
        float a0 = asrc2[s0], a1 = asrc2[s1];
        float g0 = h2[s0 * 8 + c], g1 = h2[s1 * 8 + c];
        float e0 = a0 + adv; e0 = e0 > 0.f ? e0 : NEG_SLOPE * e0;
        float e1 = a1 + adv; e1 = e1 > 0.f ? e1 : NEG_SLOPE * e1;
        float p0 = __expf(e0), p1 = __expf(e1);
        acc = fmaf(p0, g0, acc); acc = fmaf(p1, g1, acc);
        ssum += p0 + p1;
    }
    for (; j < deg; j += 8) {
        int sn = csr[beg + j];
        float e = asrc2[sn] + adv;
        e = e > 0.f ? e : NEG_SLOPE * e;
        float p = __expf(e);
        acc = fmaf(p, h2[sn * 8 + c], acc);
        ssum += p;
    }
    acc  += __shfl_xor(acc, 8);  acc  += __shfl_xor(acc, 16);  acc  += __shfl_xor(acc, 32);
    ssum += __shfl_xor(ssum, 8); ssum += __shfl_xor(ssum, 16); ssum += __shfl_xor(ssum, 32);
    float inv = 1.f / fmaxf(ssum, 1e-16f);
    if (lane < OUT_DIM) out[(size_t)node * OUT_DIM + lane] = acc * inv + b2[lane];
}

// ---------------- launch ----------------
static inline size_t rup256(size_t x) { return (x + 255) & ~(size_t)255; }

extern "C" void kernel_launch(void* const* d_in, const int* in_sizes, int n_in,
                              void* d_out, int out_size, void* d_ws, size_t ws_size,
                              hipStream_t stream)
{
    int n = in_sizes[0] / IN_DIM;       // 50000
    int E = in_sizes[1] / 2;            // 1600000
    int nbuck = (n + BMASK) >> BSHIFT;  // 391
    int nCoarse = (E + 256 * K3_EPT - 1) / (256 * K3_EPT);   // 391
    int nGemm = (n + 31) / 32;          // 1563

    const float* x   = (const float*)d_in[0];
    const int*   ei  = (const int*)d_in[1];
    const int*   srcv = ei;
    const int*   dstv = ei + E;
    const float* W1  = (const float*)d_in[2];
    const float* as1 = (const float*)d_in[3];
    const float* ad1 = (const float*)d_in[4];
    const float* b1  = (const float*)d_in[5];
    const float* W2  = (const float*)d_in[6];
    const float* as2 = (const float*)d_in[7];
    const float* ad2 = (const float*)d_in[8];
    const float* b2  = (const float*)d_in[9];
    float* out = (float*)d_out;

    char* p = (char*)d_ws;
    auto alloc = [&](size_t bytes) { char* q = p; p += rup256(bytes); return (void*)q; };
    unsigned short* h1 = (unsigned short*)alloc((size_t)n * 64 * 2);
    float* asrc1   = (float*)alloc((size_t)n * 8 * 4);
    float* adst1   = (float*)alloc((size_t)n * 8 * 4);
    float* h2      = (float*)alloc((size_t)n * 8 * 4);
    float* asrc2   = (float*)alloc((size_t)n * 4);
    float* adst2   = (float*)alloc((size_t)n * 4);
    int*   counts  = (int*)alloc((size_t)n * 4);
    int*   offsets = (int*)alloc(((size_t)n + 1) * 4);
    int*   csr     = (int*)alloc((size_t)E * 4);
    unsigned int* tmp = (unsigned int*)alloc((size_t)E * 4);
    int*   bucketCounts = (int*)alloc(512 * 4);
    int*   bucketBase   = (int*)alloc(513 * 4);
    int*   bucketCursor = (int*)alloc(512 * 4);
    unsigned short* bhi = (unsigned short*)alloc((size_t)IN_DIM * 64 * 2);
    unsigned short* blo = (unsigned short*)alloc((size_t)IN_DIM * 64 * 2);

    hipMemsetAsync(bucketCounts, 0, 512 * 4, stream);
    prep_kernel<<<128 + 512, 256, 0, stream>>>(W1, bhi, blo, dstv, bucketCounts, E, nbuck);
    bucket_scan_kernel<<<1, 512, 0, stream>>>(bucketCounts, bucketBase, bucketCursor, nbuck);
    gemm1_coarse_kernel<<<nGemm + nCoarse, 256, 0, stream>>>(
        x, bhi, blo, as1, ad1, h1, asrc1, adst1, n,
        srcv, dstv, bucketCursor, tmp, E, nGemm);
    fine_scatter_kernel<<<nbuck, 256, 0, stream>>>(
        tmp, bucketBase, csr, offsets, counts, n);
    l1_edge_kernel<<<(n + 3) / 4, 256, 0, stream>>>(
        offsets, counts, csr, asrc1, adst1, h1, b1, W2, as2, ad2, h2, asrc2, adst2, n);
    l2_edge_kernel<<<(n + 3) / 4, 256, 0, stream>>>(
        offsets, counts, csr, asrc2, adst2, h2, b2, out, n);
}

// Round 21
// 130.110 us; speedup vs baseline: 1.1089x; 1.0996x over previous
//
#include <hip/hip_runtime.h>
#include <hip/hip_bf16.h>

#define IN_DIM 512
#define HEADS 8
#define HID 8
#define OUT_DIM 7
#define NEG_SLOPE 0.2f

typedef __attribute__((ext_vector_type(8))) short short8b;   // 8 bf16 (4 VGPR)
typedef __attribute__((ext_vector_type(4))) float f32x4;

#define BSHIFT 7
#define BMASK 127
#define K3_EPT 16

__device__ __forceinline__ unsigned short f2bf_rne(float f) {
    unsigned u = __float_as_uint(f);
    unsigned r = (u + 0x7FFFu + ((u >> 16) & 1u)) >> 16;
    return (unsigned short)r;
}
__device__ __forceinline__ float bf2f(unsigned short s) {
    return __uint_as_float((unsigned)s << 16);
}

// ---------------- prep: W1 fragment-pack (blocks 0..127) ||
//                  per-block bucket histogram (blocks 128..128+nCoarse-1, NO atomics)
__global__ __launch_bounds__(256) void prep_kernel(
    const float* __restrict__ W1, unsigned short* __restrict__ bhi,
    unsigned short* __restrict__ blo,
    const int* __restrict__ dst, int* __restrict__ blockCnt, int E)
{
    __shared__ int cnt[512];
    int t = threadIdx.x;
    if (blockIdx.x < 128) {
        int i = blockIdx.x * 256 + t;       // 0..32767
        int j = i & 7;
        int lane = (i >> 3) & 63;
        int T = (i >> 9) & 3;
        int chunk = i >> 11;
        int col = 16 * T + (lane & 15);
        int k = chunk * 32 + 8 * (lane >> 4) + j;
        float w = W1[k * 64 + col];
        unsigned u = __float_as_uint(w);
        unsigned hu = u & 0xFFFF0000u;
        float rem = w - __uint_as_float(hu);
        bhi[i] = (unsigned short)(hu >> 16);
        blo[i] = (unsigned short)(__float_as_uint(rem) >> 16);
    } else {
        int hb = blockIdx.x - 128;          // 0..nCoarse-1, EXACT coarse decomposition
        cnt[t] = 0; cnt[t + 256] = 0;
        __syncthreads();
        int base = hb * (256 * K3_EPT);
        #pragma unroll
        for (int j = 0; j < K3_EPT; ++j) {
            int i = base + t + j * 256;
            if (i < E) atomicAdd(&cnt[dst[i] >> BSHIFT], 1);   // LDS only
        }
        __syncthreads();
        blockCnt[hb * 512 + t] = cnt[t];
        blockCnt[hb * 512 + 256 + t] = cnt[t + 256];
    }
}

// ---------------- scanA: per-bucket exclusive prefix over coarse blocks -----
__global__ __launch_bounds__(512) void blk_scan_kernel(
    const int* __restrict__ blockCnt, int* __restrict__ blockOfs,
    int* __restrict__ bucketTotal, int nCoarse)
{
    __shared__ int wsum[8];
    int b = blockIdx.x;                 // bucket
    int t = threadIdx.x, lane = t & 63, w = t >> 6;
    int c = (t < nCoarse) ? blockCnt[t * 512 + b] : 0;
    int inc = c;
    #pragma unroll
    for (int d = 1; d < 64; d <<= 1) {
        int u = __shfl_up(inc, d);
        if (lane >= d) inc += u;
    }
    if (lane == 63) wsum[w] = inc;
    __syncthreads();
    if (t == 0) { int run = 0; for (int k = 0; k < 8; ++k) { int tmp = wsum[k]; wsum[k] = run; run += tmp; } }
    __syncthreads();
    int excl = inc - c + wsum[w];
    if (t < nCoarse) blockOfs[t * 512 + b] = excl;
    if (t == nCoarse - 1) bucketTotal[b] = excl + c;
}

// ---------------- scanB: bucket totals -> bucketBase ----------------------
__global__ __launch_bounds__(512) void bucket_scan_kernel(
    const int* __restrict__ bucketTotal, int* __restrict__ bucketBase, int nbuck)
{
    __shared__ int wsum[8];
    int t = threadIdx.x, lane = t & 63, w = t >> 6;
    int c = (t < nbuck) ? bucketTotal[t] : 0;
    int inc = c;
    #pragma unroll
    for (int d = 1; d < 64; d <<= 1) {
        int u = __shfl_up(inc, d);
        if (lane >= d) inc += u;
    }
    if (lane == 63) wsum[w] = inc;
    __syncthreads();
    if (t == 0) { int run = 0; for (int k = 0; k < 8; ++k) { int tmp = wsum[k]; wsum[k] = run; run += tmp; } }
    __syncthreads();
    int excl = inc - c + wsum[w];
    if (t < nbuck) bucketBase[t] = excl;
    if (t == nbuck) bucketBase[t] = excl;
}

// ---------------- fused: GEMM1 (blocks 0..nGemm-1) ||
//                  coarse scatter (last nCoarse blocks, ZERO global atomics)
__global__ __launch_bounds__(256) void gemm1_coarse_kernel(
    const float* __restrict__ x,
    const unsigned short* __restrict__ bhi, const unsigned short* __restrict__ blo,
    const float* __restrict__ as1, const float* __restrict__ ad1,
    unsigned short* __restrict__ h1, float* __restrict__ asrc1, float* __restrict__ adst1,
    int n,
    const int* __restrict__ src, const int* __restrict__ dstv,
    const int* __restrict__ bucketBase, const int* __restrict__ blockOfs,
    unsigned int* __restrict__ tmp, int E, int nGemm)
{
    __shared__ float lds[4][32][68];   // 34.8 KB: gemm1 stage/partials; coarse cnt+gbase
    int t = threadIdx.x;

    if ((int)blockIdx.x >= nGemm) {
        int cb = blockIdx.x - nGemm;    // coarse block id
        int* cnt   = (int*)&lds[0][0][0];
        int* gbase = cnt + 512;
        cnt[t] = 0; cnt[t + 256] = 0;
        __syncthreads();
        int base = cb * (256 * K3_EPT);
        unsigned int pk[K3_EPT];
        unsigned int meta[K3_EPT];
        #pragma unroll
        for (int j = 0; j < K3_EPT; ++j) {
            int i = base + t + j * 256;
            if (i < E) {
                int d = dstv[i], s = src[i];
                int b = d >> BSHIFT;
                pk[j] = ((unsigned)s << 16) | (unsigned)(d & BMASK);
                int r = atomicAdd(&cnt[b], 1);      // LDS rank only
                meta[j] = ((unsigned)r << 9) | (unsigned)b;
            } else {
                meta[j] = 0xFFFFFFFFu; pk[j] = 0;
            }
        }
        __syncthreads();
        // exact global base: no atomics
        gbase[t]       = bucketBase[t]       + blockOfs[cb * 512 + t];
        gbase[t + 256] = bucketBase[t + 256] + blockOfs[cb * 512 + t + 256];
        __syncthreads();
        #pragma unroll
        for (int j = 0; j < K3_EPT; ++j) {
            if (meta[j] != 0xFFFFFFFFu) {
                int b = meta[j] & 511;
                int r = meta[j] >> 9;
                tmp[gbase[b] + r] = pk[j];
            }
        }
        return;
    }

    // ---- GEMM1 part: 32 rows, wave owns k-quarter, staged 64 k at a time ----
    int wave = t >> 6, l = t & 63;
    int il = l & 15, g = l >> 4;
    int r0 = blockIdx.x * 32;
    int kw = wave * 128;

    f32x4 acc[2][4] = {{{0.f,0.f,0.f,0.f},{0.f,0.f,0.f,0.f},{0.f,0.f,0.f,0.f},{0.f,0.f,0.f,0.f}},
                       {{0.f,0.f,0.f,0.f},{0.f,0.f,0.f,0.f},{0.f,0.f,0.f,0.f},{0.f,0.f,0.f,0.f}}};

    #pragma unroll
    for (int ph = 0; ph < 2; ++ph) {
        #pragma unroll
        for (int j = 0; j < 8; ++j) {
            int idx = j * 64 + l;          // 0..511
            int row = idx >> 4;            // 32 rows
            int kq = idx & 15;             // float4 slot in 64-float slice
            int gr = r0 + row; if (gr >= n) gr = n - 1;
            float4 v = *(const float4*)(x + (size_t)gr * IN_DIM + kw + ph * 64 + kq * 4);
            *(float4*)(&lds[wave][row][kq * 4]) = v;
        }
        #pragma unroll
        for (int itp = 0; itp < 2; ++itp) {
            int it = ph * 2 + itp;
            int chunk = wave * 4 + it;
            const short8b* bh = (const short8b*)bhi + (size_t)(chunk * 4) * 64 + l;
            const short8b* bl = (const short8b*)blo + (size_t)(chunk * 4) * 64 + l;
            short8b Bh[4], Bl[4];
            #pragma unroll
            for (int T = 0; T < 4; ++T) { Bh[T] = bh[T * 64]; Bl[T] = bl[T * 64]; }
            #pragma unroll
            for (int rg = 0; rg < 2; ++rg) {
                float av[8];
                *(float4*)(&av[0]) = *(const float4*)(&lds[wave][rg * 16 + il][32 * itp + 8 * g]);
                *(float4*)(&av[4]) = *(const float4*)(&lds[wave][rg * 16 + il][32 * itp + 8 * g + 4]);
                short8b Ahi, Alo;
                #pragma unroll
                for (int j = 0; j < 8; ++j) {
                    unsigned u = __float_as_uint(av[j]);
                    unsigned hu = u & 0xFFFF0000u;
                    float rem = av[j] - __uint_as_float(hu);
                    Ahi[j] = (short)(hu >> 16);
                    Alo[j] = (short)(__float_as_uint(rem) >> 16);
                }
                #pragma unroll
                for (int T = 0; T < 4; ++T) {
                    acc[rg][T] = __builtin_amdgcn_mfma_f32_16x16x32_bf16(Alo, Bh[T], acc[rg][T], 0, 0, 0);
                    acc[rg][T] = __builtin_amdgcn_mfma_f32_16x16x32_bf16(Ahi, Bl[T], acc[rg][T], 0, 0, 0);
                    acc[rg][T] = __builtin_amdgcn_mfma_f32_16x16x32_bf16(Ahi, Bh[T], acc[rg][T], 0, 0, 0);
                }
            }
        }
    }

    #pragma unroll
    for (int rg = 0; rg < 2; ++rg)
        #pragma unroll
        for (int T = 0; T < 4; ++T)
            #pragma unroll
            for (int r = 0; r < 4; ++r)
                lds[wave][rg * 16 + 4 * g + r][16 * T + il] = acc[rg][T][r];
    __syncthreads();

    #pragma unroll
    for (int half = 0; half < 2; ++half) {
        int i = t + half * 256;            // 0..511 items: 32 rows x 16 col4-groups
        int row = i >> 4, c0 = (i & 15) * 4;
        int grow = r0 + row;
        float v0 = lds[0][row][c0]     + lds[1][row][c0]     + lds[2][row][c0]     + lds[3][row][c0];
        float v1 = lds[0][row][c0 + 1] + lds[1][row][c0 + 1] + lds[2][row][c0 + 1] + lds[3][row][c0 + 1];
        float v2 = lds[0][row][c0 + 2] + lds[1][row][c0 + 2] + lds[2][row][c0 + 2] + lds[3][row][c0 + 2];
        float v3 = lds[0][row][c0 + 3] + lds[1][row][c0 + 3] + lds[2][row][c0 + 3] + lds[3][row][c0 + 3];
        float4 asv = *(const float4*)(as1 + c0);
        float4 adv = *(const float4*)(ad1 + c0);
        float pa = v0 * asv.x + v1 * asv.y + v2 * asv.z + v3 * asv.w;
        float pd = v0 * adv.x + v1 * adv.y + v2 * adv.z + v3 * adv.w;
        pa += __shfl_xor(pa, 1);           // partner handles i^1: same row, paired col4
        pd += __shfl_xor(pd, 1);
        if (grow < n) {
            ushort4 hb;
            hb.x = f2bf_rne(v0); hb.y = f2bf_rne(v1);
            hb.z = f2bf_rne(v2); hb.w = f2bf_rne(v3);
            *(ushort4*)(h1 + (size_t)grow * 64 + c0) = hb;
            if ((t & 1) == 0) {
                int head = (i & 15) >> 1;
                asrc1[grow * 8 + head] = pa;
                adst1[grow * 8 + head] = pd;
            }
        }
    }
}

__global__ __launch_bounds__(256) void fine_scatter_kernel(
    const unsigned int* __restrict__ tmp, const int* __restrict__ bucketBase,
    int* __restrict__ csr, int* __restrict__ offsets, int* __restrict__ counts, int n)
{
    __shared__ int cnt[128];
    __shared__ int cur[128];
    __shared__ int wsum[2];
    int b = blockIdx.x;
    int t = threadIdx.x, lane = t & 63, w = t >> 6;
    int beg = bucketBase[b], end = bucketBase[b + 1];
    if (t < 128) cnt[t] = 0;
    __syncthreads();
    for (int i = beg + t; i < end; i += 256)
        atomicAdd(&cnt[tmp[i] & BMASK], 1);
    __syncthreads();
    if (t < 128) {
        int c = cnt[t];
        int inc = c;
        #pragma unroll
        for (int d = 1; d < 64; d <<= 1) {
            int u = __shfl_up(inc, d);
            if (lane >= d) inc += u;
        }
        if (lane == 63) wsum[w] = inc;
        __syncthreads();
        if (t == 0) { int r0_ = wsum[0]; wsum[0] = 0; wsum[1] = r0_; }
        __syncthreads();
        int excl = inc - c + wsum[w];
        int node = b * 128 + t;
        if (node < n) { offsets[node] = beg + excl; counts[node] = c; }
        cur[t] = excl;
    } else {
        __syncthreads(); __syncthreads();
    }
    __syncthreads();
    for (int i = beg + t; i < end; i += 256) {
        unsigned int p = tmp[i];
        int r = atomicAdd(&cur[p & BMASK], 1);
        csr[beg + r] = (int)(p >> 16);
    }
}

// ---------------- Layer-1 edge kernel: single-pass, bf16 h1 gathers --------
__global__ __launch_bounds__(256) void l1_edge_kernel(
    const int* __restrict__ offsets, const int* __restrict__ counts,
    const int* __restrict__ csr,
    const float* __restrict__ asrc1, const float* __restrict__ adst1,
    const unsigned short* __restrict__ h1, const float* __restrict__ b1,
    const float* __restrict__ W2, const float* __restrict__ as2,
    const float* __restrict__ ad2,
    float* __restrict__ h2, float* __restrict__ asrc2, float* __restrict__ adst2,
    int n)
{
    __shared__ float w2t[8][64];
    __shared__ float s_as2[8], s_ad2[8], s_b1[64];
    __shared__ int csr_s[4][64];
    int t = threadIdx.x;
    if (t < 64) {
        #pragma unroll
        for (int j = 0; j < OUT_DIM; ++j) w2t[j][t] = W2[t * OUT_DIM + j];
        s_b1[t] = b1[t];
        if (t < OUT_DIM) { s_as2[t] = as2[t]; s_ad2[t] = ad2[t]; }
    }
    __syncthreads();

    int lane = t & 63;
    int nl = t >> 6;
    int node = blockIdx.x * 4 + nl;
    if (node >= n) return;
    int beg = offsets[node];
    int deg = counts[node];
    int q = lane >> 4;
    int il = lane & 15;
    int c0 = il * 4;
    int head = il >> 1;
    float adv = adst1[node * 8 + head];

    if (lane < deg) csr_s[nl][lane] = csr[beg + lane];
    int deg_r = deg < 64 ? deg : 64;
    const int* cs = &csr_s[nl][0];

    float4 acc = make_float4(0.f, 0.f, 0.f, 0.f);
    float ssum = 0.f;
    if (q == 0) {   // self loop
        float e = asrc1[node * 8 + head] + adv;
        e = e > 0.f ? e : NEG_SLOPE * e;
        float p = __expf(e);
        ushort4 hu = *(const ushort4*)(h1 + (size_t)node * 64 + c0);
        acc.x = p * bf2f(hu.x); acc.y = p * bf2f(hu.y);
        acc.z = p * bf2f(hu.z); acc.w = p * bf2f(hu.w);
        ssum = p;
    }
    int j = q;
    for (; j + 12 < deg_r; j += 16) {
        int s0 = cs[j];
        int s1 = cs[j + 4];
        int s2 = cs[j + 8];
        int s3 = cs[j + 12];
        float a0 = asrc1[s0 * 8 + head], a1 = asrc1[s1 * 8 + head];
        float a2 = asrc1[s2 * 8 + head], a3 = asrc1[s3 * 8 + head];
        ushort4 g0 = *(const ushort4*)(h1 + (size_t)s0 * 64 + c0);
        ushort4 g1 = *(const ushort4*)(h1 + (size_t)s1 * 64 + c0);
        ushort4 g2 = *(const ushort4*)(h1 + (size_t)s2 * 64 + c0);
        ushort4 g3 = *(const ushort4*)(h1 + (size_t)s3 * 64 + c0);
        float e0 = a0 + adv; e0 = e0 > 0.f ? e0 : NEG_SLOPE * e0;
        float e1 = a1 + adv; e1 = e1 > 0.f ? e1 : NEG_SLOPE * e1;
        float e2 = a2 + adv; e2 = e2 > 0.f ? e2 : NEG_SLOPE * e2;
        float e3 = a3 + adv; e3 = e3 > 0.f ? e3 : NEG_SLOPE * e3;
        float p0 = __expf(e0), p1 = __expf(e1);
        float p2 = __expf(e2), p3 = __expf(e3);
        acc.x = fmaf(p0, bf2f(g0.x), acc.x); acc.y = fmaf(p0, bf2f(g0.y), acc.y);
        acc.z = fmaf(p0, bf2f(g0.z), acc.z); acc.w = fmaf(p0, bf2f(g0.w), acc.w);
        acc.x = fmaf(p1, bf2f(g1.x), acc.x); acc.y = fmaf(p1, bf2f(g1.y), acc.y);
        acc.z = fmaf(p1, bf2f(g1.z), acc.z); acc.w = fmaf(p1, bf2f(g1.w), acc.w);
        acc.x = fmaf(p2, bf2f(g2.x), acc.x); acc.y = fmaf(p2, bf2f(g2.y), acc.y);
        acc.z = fmaf(p2, bf2f(g2.z), acc.z); acc.w = fmaf(p2, bf2f(g2.w), acc.w);
        acc.x = fmaf(p3, bf2f(g3.x), acc.x); acc.y = fmaf(p3, bf2f(g3.y), acc.y);
        acc.z = fmaf(p3, bf2f(g3.z), acc.z); acc.w = fmaf(p3, bf2f(g3.w), acc.w);
        ssum += (p0 + p1) + (p2 + p3);
    }
    for (; j < deg_r; j += 4) {
        int sn = cs[j];
        float a = asrc1[sn * 8 + head];
        ushort4 g = *(const ushort4*)(h1 + (size_t)sn * 64 + c0);
        float e = a + adv; e = e > 0.f ? e : NEG_SLOPE * e;
        float p = __expf(e);
        acc.x = fmaf(p, bf2f(g.x), acc.x); acc.y = fmaf(p, bf2f(g.y), acc.y);
        acc.z = fmaf(p, bf2f(g.z), acc.z); acc.w = fmaf(p, bf2f(g.w), acc.w);
        ssum += p;
    }
    for (; j < deg; j += 4) {
        int sn = csr[beg + j];
        float a = asrc1[sn * 8 + head];
        ushort4 g = *(const ushort4*)(h1 + (size_t)sn * 64 + c0);
        float e = a + adv; e = e > 0.f ? e : NEG_SLOPE * e;
        float p = __expf(e);
        acc.x = fmaf(p, bf2f(g.x), acc.x); acc.y = fmaf(p, bf2f(g.y), acc.y);
        acc.z = fmaf(p, bf2f(g.z), acc.z); acc.w = fmaf(p, bf2f(g.w), acc.w);
        ssum += p;
    }
    acc.x += __shfl_xor(acc.x, 16); acc.x += __shfl_xor(acc.x, 32);
    acc.y += __shfl_xor(acc.y, 16); acc.y += __shfl_xor(acc.y, 32);
    acc.z += __shfl_xor(acc.z, 16); acc.z += __shfl_xor(acc.z, 32);
    acc.w += __shfl_xor(acc.w, 16); acc.w += __shfl_xor(acc.w, 32);
    ssum  += __shfl_xor(ssum, 16);  ssum  += __shfl_xor(ssum, 32);
    float inv = 1.f / fmaxf(ssum, 1e-16f);

    float4 bv = *(const float4*)(&s_b1[c0]);
    float v0 = acc.x * inv + bv.x;
    float v1 = acc.y * inv + bv.y;
    float v2 = acc.z * inv + bv.z;
    float v3 = acc.w * inv + bv.w;
    v0 = v0 > 0.f ? v0 : __expf(v0) - 1.f;
    v1 = v1 > 0.f ? v1 : __expf(v1) - 1.f;
    v2 = v2 > 0.f ? v2 : __expf(v2) - 1.f;
    v3 = v3 > 0.f ? v3 : __expf(v3) - 1.f;

    float hj[OUT_DIM];
    #pragma unroll
    for (int jj = 0; jj < OUT_DIM; ++jj) {
        float4 wv = *(const float4*)(&w2t[jj][c0]);
        float p = v0 * wv.x + v1 * wv.y + v2 * wv.z + v3 * wv.w;
        p += __shfl_xor(p, 1);
        p += __shfl_xor(p, 2);
        p += __shfl_xor(p, 4);
        p += __shfl_xor(p, 8);
        hj[jj] = p;
    }
    float a_s = 0.f, a_d = 0.f;
    #pragma unroll
    for (int jj = 0; jj < OUT_DIM; ++jj) { a_s += hj[jj] * s_as2[jj]; a_d += hj[jj] * s_ad2[jj]; }
    if (lane < 8) h2[node * 8 + lane] = (lane < OUT_DIM) ? hj[lane] : 0.f;
    if (lane == 0) { asrc2[node] = a_s; adst2[node] = a_d; }
}

// ---------------- Layer-2 edge kernel: single-pass -> final logits --------
__global__ __launch_bounds__(256) void l2_edge_kernel(
    const int* __restrict__ offsets, const int* __restrict__ counts,
    const int* __restrict__ csr,
    const float* __restrict__ asrc2, const float* __restrict__ adst2,
    const float* __restrict__ h2, const float* __restrict__ b2,
    float* __restrict__ out, int n)
{
    int t = threadIdx.x, lane = t & 63;
    int node = blockIdx.x * 4 + (t >> 6);
    if (node >= n) return;
    int beg = offsets[node];
    int deg = counts[node];
    float adv = adst2[node];

    int c = lane & 7, slot = lane >> 3;
    float acc = 0.f, ssum = 0.f;
    if (slot == 0) {
        float e = asrc2[node] + adv;
        e = e > 0.f ? e : NEG_SLOPE * e;
        float p = __expf(e);
        acc = p * h2[node * 8 + c];
        ssum = p;
    }
    int j = slot;
    for (; j + 8 < deg; j += 16) {
        int s0 = csr[beg + j], s1 = csr[beg + j + 8];
        float a0 = asrc2[s0], a1 = asrc2[s1];
        float g0 = h2[s0 * 8 + c], g1 = h2[s1 * 8 + c];
        float e0 = a0 + adv; e0 = e0 > 0.f ? e0 : NEG_SLOPE * e0;
        float e1 = a1 + adv; e1 = e1 > 0.f ? e1 : NEG_SLOPE * e1;
        float p0 = __expf(e0), p1 = __expf(e1);
        acc = fmaf(p0, g0, acc); acc = fmaf(p1, g1, acc);
        ssum += p0 + p1;
    }
    for (; j < deg; j += 8) {
        int sn = csr[beg + j];
        float e = asrc2[sn] + adv;
        e = e > 0.f ? e : NEG_SLOPE * e;
        float p = __expf(e);
        acc = fmaf(p, h2[sn * 8 + c], acc);
        ssum += p;
    }
    acc  += __shfl_xor(acc, 8);  acc  += __shfl_xor(acc, 16);  acc  += __shfl_xor(acc, 32);
    ssum += __shfl_xor(ssum, 8); ssum += __shfl_xor(ssum, 16); ssum += __shfl_xor(ssum, 32);
    float inv = 1.f / fmaxf(ssum, 1e-16f);
    if (lane < OUT_DIM) out[(size_t)node * OUT_DIM + lane] = acc * inv + b2[lane];
}

// ---------------- launch ----------------
static inline size_t rup256(size_t x) { return (x + 255) & ~(size_t)255; }

extern "C" void kernel_launch(void* const* d_in, const int* in_sizes, int n_in,
                              void* d_out, int out_size, void* d_ws, size_t ws_size,
                              hipStream_t stream)
{
    int n = in_sizes[0] / IN_DIM;       // 50000
    int E = in_sizes[1] / 2;            // 1600000
    int nbuck = (n + BMASK) >> BSHIFT;  // 391
    int nCoarse = (E + 256 * K3_EPT - 1) / (256 * K3_EPT);   // 391
    int nGemm = (n + 31) / 32;          // 1563

    const float* x   = (const float*)d_in[0];
    const int*   ei  = (const int*)d_in[1];
    const int*   srcv = ei;
    const int*   dstv = ei + E;
    const float* W1  = (const float*)d_in[2];
    const float* as1 = (const float*)d_in[3];
    const float* ad1 = (const float*)d_in[4];
    const float* b1  = (const float*)d_in[5];
    const float* W2  = (const float*)d_in[6];
    const float* as2 = (const float*)d_in[7];
    const float* ad2 = (const float*)d_in[8];
    const float* b2  = (const float*)d_in[9];
    float* out = (float*)d_out;

    char* p = (char*)d_ws;
    auto alloc = [&](size_t bytes) { char* q = p; p += rup256(bytes); return (void*)q; };
    unsigned short* h1 = (unsigned short*)alloc((size_t)n * 64 * 2);
    float* asrc1   = (float*)alloc((size_t)n * 8 * 4);
    float* adst1   = (float*)alloc((size_t)n * 8 * 4);
    float* h2      = (float*)alloc((size_t)n * 8 * 4);
    float* asrc2   = (float*)alloc((size_t)n * 4);
    float* adst2   = (float*)alloc((size_t)n * 4);
    int*   counts  = (int*)alloc((size_t)n * 4);
    int*   offsets = (int*)alloc(((size_t)n + 1) * 4);
    int*   csr     = (int*)alloc((size_t)E * 4);
    unsigned int* tmp = (unsigned int*)alloc((size_t)E * 4);
    int*   blockCnt = (int*)alloc((size_t)nCoarse * 512 * 4);
    int*   blockOfs = (int*)alloc((size_t)nCoarse * 512 * 4);
    int*   bucketTotal = (int*)alloc(512 * 4);
    int*   bucketBase  = (int*)alloc(513 * 4);
    unsigned short* bhi = (unsigned short*)alloc((size_t)IN_DIM * 64 * 2);
    unsigned short* blo = (unsigned short*)alloc((size_t)IN_DIM * 64 * 2);

    prep_kernel<<<128 + nCoarse, 256, 0, stream>>>(W1, bhi, blo, dstv, blockCnt, E);
    blk_scan_kernel<<<nbuck, 512, 0, stream>>>(blockCnt, blockOfs, bucketTotal, nCoarse);
    bucket_scan_kernel<<<1, 512, 0, stream>>>(bucketTotal, bucketBase, nbuck);
    gemm1_coarse_kernel<<<nGemm + nCoarse, 256, 0, stream>>>(
        x, bhi, blo, as1, ad1, h1, asrc1, adst1, n,
        srcv, dstv, bucketBase, blockOfs, tmp, E, nGemm);
    fine_scatter_kernel<<<nbuck, 256, 0, stream>>>(
        tmp, bucketBase, csr, offsets, counts, n);
    l1_edge_kernel<<<(n + 3) / 4, 256, 0, stream>>>(
        offsets, counts, csr, asrc1, adst1, h1, b1, W2, as2, ad2, h2, asrc2, adst2, n);
    l2_edge_kernel<<<(n + 3) / 4, 256, 0, stream>>>(
        offsets, counts, csr, asrc2, adst2, h2, b2, out, n);
}